// Round 8
// baseline (313.741 us; speedup 1.0000x reference)
//
#include <hip/hip_runtime.h>

#define B_ 4
#define N_ 2048
#define R_ (B_ * N_)      // 8192 rows
#define HID_ 256
#define EMB_ 64
#define IN_DIM_ 70
#define H_ 4
#define HEAD_ 64
#define FFN_ 512
#define LAYERS_ 4

typedef __attribute__((ext_vector_type(8))) short short8;
typedef __attribute__((ext_vector_type(4))) float f32x4;
typedef unsigned short ushort;

static __device__ __forceinline__ ushort f2bf(float f) {
    unsigned u = __builtin_bit_cast(unsigned, f);
    u += 0x7fffu + ((u >> 16) & 1u);   // RNE
    return (ushort)(u >> 16);
}
static __device__ __forceinline__ float bf2f(ushort u) {
    unsigned x = ((unsigned)u) << 16;
    return __builtin_bit_cast(float, x);
}

#define GLOAD_LDS16(g, l)                                              \
    __builtin_amdgcn_global_load_lds(                                  \
        (const __attribute__((address_space(1))) void*)(g),            \
        (__attribute__((address_space(3))) void*)(l), 16, 0, 0)

// ---------------------------------------------------------------------------
// Pack all weights to bf16, transposed [c][k] layout, in one kernel.
// ---------------------------------------------------------------------------
__global__ __launch_bounds__(256) void pack_weights(const float* __restrict__ valW,
                                                    const float* __restrict__ attnW,
                                                    const float* __restrict__ ffnW1,
                                                    const float* __restrict__ ffnW2,
                                                    const float* __restrict__ outW1,
                                                    ushort* __restrict__ wp) {
    int idx = blockIdx.x * 256 + threadIdx.x;
    float v;
    if (idx < 262144) {
        int l = idx >> 16, c = (idx >> 8) & 255, k = idx & 255;
        v = valW[((l * 4 + (c >> 6)) * 256 + k) * 64 + (c & 63)];
    } else if (idx < 524288) {
        int i2 = idx - 262144;
        int l = i2 >> 16, c = (i2 >> 8) & 255, k = i2 & 255;
        v = attnW[l * 65536 + k * 256 + c];
    } else if (idx < 1048576) {
        int i2 = idx - 524288;
        int l = i2 >> 17, c = (i2 >> 8) & 511, k = i2 & 255;
        v = ffnW1[l * 131072 + k * 512 + c];
    } else if (idx < 1572864) {
        int i2 = idx - 1048576;
        int l = i2 >> 17, c = (i2 >> 9) & 255, k = i2 & 511;
        v = ffnW2[l * 131072 + k * 256 + c];
    } else {
        int i2 = idx - 1572864;
        int c = i2 >> 8, k = i2 & 255;
        v = outW1[k * 256 + c];
    }
    wp[idx] = f2bf(v);
}

// ---------------------------------------------------------------------------
// Input MLP: feats = relu(concat @ in_W + in_b); dual write fp32 + bf16
// ---------------------------------------------------------------------------
__global__ __launch_bounds__(256) void input_mlp(const float* __restrict__ xc,
                                                 const float* __restrict__ emb,
                                                 const float* __restrict__ lat,
                                                 const float* __restrict__ W,
                                                 const float* __restrict__ b,
                                                 float* __restrict__ feats,
                                                 ushort* __restrict__ featsb) {
    __shared__ float xr[8][IN_DIM_ + 2];
    int t = threadIdx.x;
    int row0 = blockIdx.x * 8;
    for (int idx = t; idx < 8 * IN_DIM_; idx += 256) {
        int r = idx / IN_DIM_, f = idx % IN_DIM_;
        int rr = row0 + r;
        float v;
        if (f < 3)       v = xc[rr * 3 + f];
        else if (f < 67) v = emb[rr * EMB_ + (f - 3)];
        else             v = lat[rr * 3 + (f - 67)];
        xr[r][f] = v;
    }
    __syncthreads();
    float acc[8] = {0.f, 0.f, 0.f, 0.f, 0.f, 0.f, 0.f, 0.f};
    for (int f = 0; f < IN_DIM_; ++f) {
        float w = W[f * HID_ + t];
#pragma unroll
        for (int r = 0; r < 8; ++r) acc[r] += xr[r][f] * w;
    }
    float bb = b[t];
#pragma unroll
    for (int r = 0; r < 8; ++r) {
        float v = fmaxf(acc[r] + bb, 0.f);
        feats[(row0 + r) * HID_ + t] = v;
        featsb[(row0 + r) * HID_ + t] = f2bf(v);
    }
}

// ---------------------------------------------------------------------------
// MFMA bf16 GEMM, double-buffered K-loop (MODE3: V-proj, MODE4: final).
// ---------------------------------------------------------------------------
template <int KD, int COLS, int MODE>
__global__ __launch_bounds__(256) void gemmM(const ushort* __restrict__ A,
                                             const ushort* __restrict__ Bt,
                                             const float* __restrict__ bias,
                                             const float* __restrict__ resid,
                                             const float* __restrict__ lng,
                                             const float* __restrict__ lnb,
                                             ushort* __restrict__ outb,
                                             float* __restrict__ outf) {
    __shared__ __align__(16) char lds[69632];   // As[2]:4KB | Ws[2]:64KB
    int t = threadIdx.x;
    int l = t & 63, w = t >> 6;
    int lr = l & 15, g = l >> 4;
    int row0 = blockIdx.x * 16;
    int cbase = blockIdx.y * 256;
    f32x4 acc[4] = {};

    const ushort* srcA = A + (size_t)(row0 + (t >> 3)) * KD + (((t & 7) ^ ((t >> 3) & 7)) << 3);
    const ushort* srcB[8];
#pragma unroll
    for (int q = 0; q < 8; ++q) {
        int cl = q * 32 + (t >> 3);
        srcB[q] = Bt + (size_t)(cbase + cl) * KD + (((t & 7) ^ (cl & 7)) << 3);
    }

    auto STAGE = [&](int buf) {
        if (t < 128) GLOAD_LDS16(srcA, lds + buf * 2048 + t * 16);
#pragma unroll
        for (int q = 0; q < 8; ++q)
            GLOAD_LDS16(srcB[q], lds + 4096 + buf * 32768 + q * 4096 + t * 16);
        srcA += 64;
#pragma unroll
        for (int q = 0; q < 8; ++q) srcB[q] += 64;
    };

    int sw_a = (lr & 7) << 4;
    int aoff = lr * 128;
    constexpr int CH = KD / 64;

    STAGE(0);
#pragma unroll
    for (int c = 0; c < CH; ++c) {
        __syncthreads();
        if (c + 1 < CH) STAGE((c + 1) & 1);
        const char* As = lds + (c & 1) * 2048;
        const char* Ws = lds + 4096 + (c & 1) * 32768;

        short8 a0 = *(const short8*)(As + aoff + ((g * 16) ^ sw_a));
        short8 a1 = *(const short8*)(As + aoff + ((64 + g * 16) ^ sw_a));
#pragma unroll
        for (int n = 0; n < 4; ++n) {
            int cc = w * 64 + n * 16 + lr;
            const char* cb = Ws + cc * 128;
            int sw = (cc & 7) << 4;
            short8 b0 = *(const short8*)(cb + ((g * 16) ^ sw));
            short8 b1 = *(const short8*)(cb + ((64 + g * 16) ^ sw));
            acc[n] = __builtin_amdgcn_mfma_f32_16x16x32_bf16(a0, b0, acc[n], 0, 0, 0);
            acc[n] = __builtin_amdgcn_mfma_f32_16x16x32_bf16(a1, b1, acc[n], 0, 0, 0);
        }
    }
    __syncthreads();

    if constexpr (MODE == 3) {
        ushort(*Ts)[24] = (ushort(*)[24])lds;   // [256][24]
#pragma unroll
        for (int n = 0; n < 4; ++n) {
            int c = w * 64 + n * 16 + lr;
            float bi = bias[c];
#pragma unroll
            for (int r = 0; r < 4; ++r)
                Ts[c][g * 4 + r] = f2bf(acc[n][r] + bi);
        }
        __syncthreads();
        {
            int c = t;
            int b = row0 >> 11;
            int n0 = row0 & 2047;
            ushort* dst = outb + ((size_t)(b * 256 + c)) * 2048 + n0;
            uint4 v0 = *(uint4*)&Ts[c][0];
            uint4 v1 = *(uint4*)&Ts[c][8];
            *(uint4*)dst = v0;
            *(uint4*)(dst + 8) = v1;
        }
    } else {  // MODE 4
        const float* W2 = resid;    // [256][3]
        const float* b2 = lng;      // [3]
        ushort(*Ts)[264] = (ushort(*)[264])lds;  // [16][264]
#pragma unroll
        for (int n = 0; n < 4; ++n) {
            int c = w * 64 + n * 16 + lr;
            float bi = bias[c];
#pragma unroll
            for (int r = 0; r < 4; ++r)
                Ts[g * 4 + r][c] = f2bf(fmaxf(acc[n][r] + bi, 0.f));
        }
        __syncthreads();
        int row = t >> 4, s = t & 15;
        float p0 = 0.f, p1 = 0.f, p2 = 0.f;
#pragma unroll
        for (int e = 0; e < 16; ++e) {
            float x = bf2f(Ts[row][s * 16 + e]);
            const float* wr = &W2[(s * 16 + e) * 3];
            p0 += x * wr[0];
            p1 += x * wr[1];
            p2 += x * wr[2];
        }
#pragma unroll
        for (int off = 1; off < 16; off <<= 1) {
            p0 += __shfl_xor(p0, off, 64);
            p1 += __shfl_xor(p1, off, 64);
            p2 += __shfl_xor(p2, off, 64);
        }
        if (s == 0) {
            int gr = row0 + row;
            outf[gr * 3 + 0] = p0 + b2[0];
            outf[gr * 3 + 1] = p1 + b2[1];
            outf[gr * 3 + 2] = p2 + b2[2];
        }
    }
}

// ---------------------------------------------------------------------------
// gemmA: fused attn-combine + attn-proj + LN1 (unchanged from R7).
// ---------------------------------------------------------------------------
__global__ __launch_bounds__(256) void gemmA(const ushort* __restrict__ op,
                                             const float* __restrict__ dp,
                                             const ushort* __restrict__ Bt,
                                             const float* __restrict__ bias,
                                             const float* __restrict__ resid,
                                             const float* __restrict__ lng,
                                             const float* __restrict__ lnb,
                                             ushort* __restrict__ outb,
                                             float* __restrict__ outf) {
    __shared__ __align__(16) char lds[69632];
    int t = threadIdx.x;
    int l = t & 63, w = t >> 6;
    int lr = l & 15, g = l >> 4;
    int row0 = blockIdx.x * 16;
    f32x4 acc[4] = {};

    const ushort* srcB[8];
#pragma unroll
    for (int q = 0; q < 8; ++q) {
        int cl = q * 32 + (t >> 3);
        srcB[q] = Bt + (size_t)cl * 256 + (((t & 7) ^ (cl & 7)) << 3);
    }
    auto STAGE_B = [&](int buf) {
#pragma unroll
        for (int q = 0; q < 8; ++q)
            GLOAD_LDS16(srcB[q], lds + 4096 + buf * 32768 + q * 4096 + t * 16);
#pragma unroll
        for (int q = 0; q < 8; ++q) srcB[q] += 64;
    };

    int arow = t >> 3;
    int kslot = (t & 7) ^ (arow & 7);
    const ushort* asrc = op + (size_t)(row0 + arow) * 256 + (kslot << 3);
    float inv4[4] = {1.f, 1.f, 1.f, 1.f};
    if (t < 128) {
        int grow = row0 + arow;
#pragma unroll
        for (int hq = 0; hq < 4; ++hq) {
            float d = 1e-8f;
#pragma unroll
            for (int p = 0; p < 4; ++p) d += dp[(p * R_ + grow) * 4 + hq];
            inv4[hq] = 1.f / d;
        }
    }
    uint4 ar0, ar1, ar2, ar3;
    auto ALOAD = [&](int c) {
        if (t < 128) {
            const ushort* s0 = asrc + c * 64;
            ar0 = *(const uint4*)s0;
            ar1 = *(const uint4*)(s0 + (size_t)R_ * 256);
            ar2 = *(const uint4*)(s0 + (size_t)2 * R_ * 256);
            ar3 = *(const uint4*)(s0 + (size_t)3 * R_ * 256);
        }
    };
    auto APROC = [&](int buf, int c) {
        if (t < 128) {
            const ushort* p0 = (const ushort*)&ar0;
            const ushort* p1 = (const ushort*)&ar1;
            const ushort* p2 = (const ushort*)&ar2;
            const ushort* p3 = (const ushort*)&ar3;
            float iv = inv4[c];
            float s[8];
#pragma unroll
            for (int e = 0; e < 8; ++e)
                s[e] = ((bf2f(p0[e]) + bf2f(p1[e])) + (bf2f(p2[e]) + bf2f(p3[e]))) * iv;
            union { unsigned u[4]; uint4 v; } pk;
#pragma unroll
            for (int q = 0; q < 4; ++q)
                asm("v_cvt_pk_bf16_f32 %0, %1, %2"
                    : "=v"(pk.u[q]) : "v"(s[2 * q]), "v"(s[2 * q + 1]));
            *(uint4*)(lds + buf * 2048 + t * 16) = pk.v;
        }
    };

    int sw_a = (lr & 7) << 4;
    int aoff = lr * 128;

    STAGE_B(0);
    ALOAD(0);
    APROC(0, 0);
#pragma unroll
    for (int c = 0; c < 4; ++c) {
        __syncthreads();
        if (c + 1 < 4) { STAGE_B((c + 1) & 1); ALOAD(c + 1); }
        const char* As = lds + (c & 1) * 2048;
        const char* Ws = lds + 4096 + (c & 1) * 32768;

        short8 a0 = *(const short8*)(As + aoff + ((g * 16) ^ sw_a));
        short8 a1 = *(const short8*)(As + aoff + ((64 + g * 16) ^ sw_a));
#pragma unroll
        for (int n = 0; n < 4; ++n) {
            int cc = w * 64 + n * 16 + lr;
            const char* cb = Ws + cc * 128;
            int sw = (cc & 7) << 4;
            short8 b0 = *(const short8*)(cb + ((g * 16) ^ sw));
            short8 b1 = *(const short8*)(cb + ((64 + g * 16) ^ sw));
            acc[n] = __builtin_amdgcn_mfma_f32_16x16x32_bf16(a0, b0, acc[n], 0, 0, 0);
            acc[n] = __builtin_amdgcn_mfma_f32_16x16x32_bf16(a1, b1, acc[n], 0, 0, 0);
        }
        if (c + 1 < 4) APROC((c + 1) & 1, c + 1);
    }
    __syncthreads();

    float* red1 = (float*)lds;
    float* red2 = (float*)(lds + 512);
    float vals[4][4];
    float s1[4] = {0.f, 0.f, 0.f, 0.f}, s2[4] = {0.f, 0.f, 0.f, 0.f};
#pragma unroll
    for (int n = 0; n < 4; ++n) {
        int c = w * 64 + n * 16 + lr;
        float bi = bias[c];
#pragma unroll
        for (int r = 0; r < 4; ++r) {
            int row = row0 + g * 4 + r;
            float v = acc[n][r] + bi + resid[(size_t)row * 256 + c];
            vals[n][r] = v;
            s1[r] += v;
            s2[r] += v * v;
        }
    }
#pragma unroll
    for (int off = 1; off < 16; off <<= 1) {
#pragma unroll
        for (int r = 0; r < 4; ++r) {
            s1[r] += __shfl_xor(s1[r], off, 64);
            s2[r] += __shfl_xor(s2[r], off, 64);
        }
    }
    if (lr == 0) {
#pragma unroll
        for (int r = 0; r < 4; ++r) {
            red1[(g * 4 + r) * 4 + w] = s1[r];
            red2[(g * 4 + r) * 4 + w] = s2[r];
        }
    }
    __syncthreads();
#pragma unroll
    for (int n = 0; n < 4; ++n) {
        int c = w * 64 + n * 16 + lr;
        float gg = lng[c], bb = lnb[c];
#pragma unroll
        for (int r = 0; r < 4; ++r) {
            int rr = g * 4 + r;
            float m1 = red1[rr * 4] + red1[rr * 4 + 1] + red1[rr * 4 + 2] + red1[rr * 4 + 3];
            float m2 = red2[rr * 4] + red2[rr * 4 + 1] + red2[rr * 4 + 2] + red2[rr * 4 + 3];
            float mu = m1 * (1.f / 256.f);
            float var = m2 * (1.f / 256.f) - mu * mu;
            float rstd = rsqrtf(var + 1e-5f);
            int row = row0 + rr;
            float o = (vals[n][r] - mu) * rstd * gg + bb;
            outf[(size_t)row * 256 + c] = o;
            outb[(size_t)row * 256 + c] = f2bf(o);
        }
    }
}

// ---------------------------------------------------------------------------
// gemmF: fused FFN1 + ReLU + FFN2 + LN2 (unchanged from R7).
// ---------------------------------------------------------------------------
__global__ __launch_bounds__(256) void gemmF(const ushort* __restrict__ A,
                                             const ushort* __restrict__ W1t,
                                             const float* __restrict__ b1,
                                             const ushort* __restrict__ W2t,
                                             const float* __restrict__ b2,
                                             const float* __restrict__ resid,
                                             const float* __restrict__ lng,
                                             const float* __restrict__ lnb,
                                             ushort* __restrict__ outb,
                                             float* __restrict__ outf) {
    __shared__ __align__(16) char lds[57344];
    char* Asp = lds;
    char* Wsp = lds + 8192;
    char* hidp = lds + 40960;

    int t = threadIdx.x;
    int l = t & 63, w = t >> 6;
    int lr = l & 15, g = l >> 4;
    int row0 = blockIdx.x * 16;
    int sw_a = (lr & 7) << 4;

#pragma unroll
    for (int shot = 0; shot < 2; ++shot) {
        int si = shot * 256 + t;
        int row = si >> 5, sl = si & 31;
        const ushort* src = A + (size_t)(row0 + row) * 256 + ((sl ^ (row & 7)) << 3);
        GLOAD_LDS16(src, Asp + si * 16);
    }

    uint4 wr0, wr1, wr2, wr3, wr4, wr5, wr6, wr7;
    auto WLOAD1 = [&](int ch, int c) {
        const ushort* base = W1t + c * 64;
#pragma unroll
        for (int q = 0; q < 8; ++q) {
            int cl = ch * 256 + q * 32 + (t >> 3);
            const uint4* s = (const uint4*)(base + (size_t)cl * 256 + (((t & 7) ^ (cl & 7)) << 3));
            uint4 v = *s;
            if (q == 0) wr0 = v; else if (q == 1) wr1 = v; else if (q == 2) wr2 = v;
            else if (q == 3) wr3 = v; else if (q == 4) wr4 = v; else if (q == 5) wr5 = v;
            else if (q == 6) wr6 = v; else wr7 = v;
        }
    };
    auto WLOAD2 = [&](int c) {
        const ushort* base = W2t + c * 64;
#pragma unroll
        for (int q = 0; q < 8; ++q) {
            int cl = q * 32 + (t >> 3);
            const uint4* s = (const uint4*)(base + (size_t)cl * 512 + (((t & 7) ^ (cl & 7)) << 3));
            uint4 v = *s;
            if (q == 0) wr0 = v; else if (q == 1) wr1 = v; else if (q == 2) wr2 = v;
            else if (q == 3) wr3 = v; else if (q == 4) wr4 = v; else if (q == 5) wr5 = v;
            else if (q == 6) wr6 = v; else wr7 = v;
        }
    };
    auto WSTORE = [&]() {
        *(uint4*)(Wsp + 0 * 4096 + t * 16) = wr0;
        *(uint4*)(Wsp + 1 * 4096 + t * 16) = wr1;
        *(uint4*)(Wsp + 2 * 4096 + t * 16) = wr2;
        *(uint4*)(Wsp + 3 * 4096 + t * 16) = wr3;
        *(uint4*)(Wsp + 4 * 4096 + t * 16) = wr4;
        *(uint4*)(Wsp + 5 * 4096 + t * 16) = wr5;
        *(uint4*)(Wsp + 6 * 4096 + t * 16) = wr6;
        *(uint4*)(Wsp + 7 * 4096 + t * 16) = wr7;
    };

    WLOAD1(0, 0);

#pragma unroll
    for (int ch = 0; ch < 2; ++ch) {
        f32x4 acc[4] = {};
#pragma unroll
        for (int c = 0; c < 4; ++c) {
            __syncthreads();
            WSTORE();
            __syncthreads();
            if (c < 3) WLOAD1(ch, c + 1);
            else if (ch == 0) WLOAD1(1, 0);
            else WLOAD2(0);

            short8 a0 = *(const short8*)(Asp + lr * 512 + ((c * 128 + g * 16) ^ sw_a));
            short8 a1 = *(const short8*)(Asp + lr * 512 + ((c * 128 + 64 + g * 16) ^ sw_a));
#pragma unroll
            for (int n = 0; n < 4; ++n) {
                int cc = w * 64 + n * 16 + lr;
                const char* cb = Wsp + cc * 128;
                int sw = (cc & 7) << 4;
                short8 b0 = *(const short8*)(cb + ((g * 16) ^ sw));
                short8 b1 = *(const short8*)(cb + ((64 + g * 16) ^ sw));
                acc[n] = __builtin_amdgcn_mfma_f32_16x16x32_bf16(a0, b0, acc[n], 0, 0, 0);
                acc[n] = __builtin_amdgcn_mfma_f32_16x16x32_bf16(a1, b1, acc[n], 0, 0, 0);
            }
        }
#pragma unroll
        for (int n = 0; n < 4; ++n) {
            int c = w * 64 + n * 16 + lr;
            float bi = b1[ch * 256 + c];
#pragma unroll
            for (int r = 0; r < 4; ++r) {
                int rw = g * 4 + r;
                float v = fmaxf(acc[n][r] + bi, 0.f);
                int byte = rw * 1024 + (((ch * 256 + c) * 2) ^ ((rw & 7) << 4));
                *(ushort*)(hidp + byte) = f2bf(v);
            }
        }
    }

    f32x4 acc2[4] = {};
#pragma unroll
    for (int c = 0; c < 8; ++c) {
        __syncthreads();
        WSTORE();
        __syncthreads();
        if (c < 7) WLOAD2(c + 1);

        short8 a0 = *(const short8*)(hidp + lr * 1024 + ((c * 128 + g * 16) ^ sw_a));
        short8 a1 = *(const short8*)(hidp + lr * 1024 + ((c * 128 + 64 + g * 16) ^ sw_a));
#pragma unroll
        for (int n = 0; n < 4; ++n) {
            int cc = w * 64 + n * 16 + lr;
            const char* cb = Wsp + cc * 128;
            int sw = (cc & 7) << 4;
            short8 b0 = *(const short8*)(cb + ((g * 16) ^ sw));
            short8 b1 = *(const short8*)(cb + ((64 + g * 16) ^ sw));
            acc2[n] = __builtin_amdgcn_mfma_f32_16x16x32_bf16(a0, b0, acc2[n], 0, 0, 0);
            acc2[n] = __builtin_amdgcn_mfma_f32_16x16x32_bf16(a1, b1, acc2[n], 0, 0, 0);
        }
    }
    __syncthreads();

    float* red1 = (float*)lds;
    float* red2 = (float*)(lds + 512);
    float vals[4][4];
    float s1[4] = {0.f, 0.f, 0.f, 0.f}, s2[4] = {0.f, 0.f, 0.f, 0.f};
#pragma unroll
    for (int n = 0; n < 4; ++n) {
        int c = w * 64 + n * 16 + lr;
        float bi = b2[c];
#pragma unroll
        for (int r = 0; r < 4; ++r) {
            int row = row0 + g * 4 + r;
            float v = acc2[n][r] + bi + resid[(size_t)row * 256 + c];
            vals[n][r] = v;
            s1[r] += v;
            s2[r] += v * v;
        }
    }
#pragma unroll
    for (int off = 1; off < 16; off <<= 1) {
#pragma unroll
        for (int r = 0; r < 4; ++r) {
            s1[r] += __shfl_xor(s1[r], off, 64);
            s2[r] += __shfl_xor(s2[r], off, 64);
        }
    }
    if (lr == 0) {
#pragma unroll
        for (int r = 0; r < 4; ++r) {
            red1[(g * 4 + r) * 4 + w] = s1[r];
            red2[(g * 4 + r) * 4 + w] = s2[r];
        }
    }
    __syncthreads();
#pragma unroll
    for (int n = 0; n < 4; ++n) {
        int c = w * 64 + n * 16 + lr;
        float gg = lng[c], bb = lnb[c];
#pragma unroll
        for (int r = 0; r < 4; ++r) {
            int rr = g * 4 + r;
            float m1 = red1[rr * 4] + red1[rr * 4 + 1] + red1[rr * 4 + 2] + red1[rr * 4 + 3];
            float m2 = red2[rr * 4] + red2[rr * 4 + 1] + red2[rr * 4 + 2] + red2[rr * 4 + 3];
            float mu = m1 * (1.f / 256.f);
            float var = m2 * (1.f / 256.f) - mu * mu;
            float rstd = rsqrtf(var + 1e-5f);
            int row = row0 + rr;
            float o = (vals[n][r] - mu) * rstd * gg + bb;
            outf[(size_t)row * 256 + c] = o;
            outb[(size_t)row * 256 + c] = f2bf(o);
        }
    }
}

// ---------------------------------------------------------------------------
// MFMA RBF attention, M_rep=2: each wave owns 32 i-rows (2 A-frags), so the
// 8 V B-frag + 8 cjv LDS reads per kk are amortized over 2x rows (LDS read
// traffic per output halves vs R7). Block = 4 waves x 32 rows = 128 i-rows.
// Grid 512 (16 ib x 4 b x 2 hp x 4 sj), XCD-decoded. opart/dpart unchanged.
// ---------------------------------------------------------------------------
__global__ __launch_bounds__(256, 2) void attn_mfma(const float* __restrict__ xc,
                                                    const ushort* __restrict__ Vt,
                                                    ushort* __restrict__ opart,
                                                    float* __restrict__ dpart) {
    __shared__ __align__(16) char Vs[2][16384];
    __shared__ __align__(16) float4 cjv[2][64];

    int t = threadIdx.x;
    int l = t & 63, w = t >> 6;
    int g = l >> 4, lr = l & 15;

    int f = blockIdx.x;                  // 512 blocks
    int xcd = f & 7, s = f >> 3;         // s: 0..63
    int combo = xcd + 8 * (s >> 4);      // 0..31
    int ib = s & 15;                     // 16 i-blocks of 128 rows
    int b = combo & 3;
    int z = combo >> 2;
    int hp = z & 1, sj = z >> 1;
    int i_base = ib * 128;
    int hc = hp * 128;
    int j0 = sj * (N_ / 4);
    const float* xb = xc + (size_t)b * N_ * 3;

    int h0 = hp * 2;
    float inv0 = (h0 == 0) ? 4.f : 0.25f;
    float ch0 = -inv0 * 1.44269504088896f;
    float ch1 = ch0 * 0.25f;

    // two row-fragments per wave: rows = i_base + af*64 + w*16 + lr
    float cix[2], ciy[2], ciz[2], ri2[2];
#pragma unroll
    for (int af = 0; af < 2; ++af) {
        const float* cip = &xb[(i_base + af * 64 + w * 16 + lr) * 3];
        cix[af] = cip[0]; ciy[af] = cip[1]; ciz[af] = cip[2];
        ri2[af] = cix[af] * cix[af] + ciy[af] * ciy[af] + ciz[af] * ciz[af];
    }

    const ushort* VtB = Vt + ((size_t)b * 256 + hc) * 2048 + j0;
    const ushort* vsrc[4];
    {
        int ss = t & 7;
#pragma unroll
        for (int q = 0; q < 4; ++q) {
            int cl = q * 32 + (t >> 3);
            vsrc[q] = VtB + (size_t)cl * 2048 + ((ss ^ (cl & 7)) << 3);
        }
    }
    auto STAGEV = [&](int buf, int jt) {
#pragma unroll
        for (int q = 0; q < 4; ++q)
            GLOAD_LDS16(vsrc[q] + jt, &Vs[buf][q * 4096 + t * 16]);
    };

    f32x4 acc0[2][4] = {}, acc1[2][4] = {};
    f32x4 accd0[2] = {}, accd1[2] = {};
    short8 ones = {0x3F80, 0x3F80, 0x3F80, 0x3F80, 0x3F80, 0x3F80, 0x3F80, 0x3F80};

    STAGEV(0, 0);
    if (t < 64) {
        const float* p = &xb[(j0 + t) * 3];
        float x = p[0], y = p[1], zz = p[2];
        cjv[0][t] = make_float4(x, y, zz, x * x + y * y + zz * zz);
    }

    constexpr int NT = (N_ / 4) / 64;   // 8 tiles
    for (int tt = 0; tt < NT; ++tt) {
        int cur = tt & 1;
        __syncthreads();
        if (tt + 1 < NT) {
            STAGEV(cur ^ 1, (tt + 1) * 64);
            if (t < 64) {
                const float* p = &xb[(j0 + (tt + 1) * 64 + t) * 3];
                float x = p[0], y = p[1], zz = p[2];
                cjv[cur ^ 1][t] = make_float4(x, y, zz, x * x + y * y + zz * zz);
            }
        }
        const char* buf = Vs[cur];
#pragma unroll
        for (int kk = 0; kk < 2; ++kk) {
            // shared j-coords for this kk (8 LDS broadcast reads, reused 2 af x 2 h)
            float4 cv[8];
#pragma unroll
            for (int e = 0; e < 8; ++e) cv[e] = cjv[cur][kk * 32 + g * 8 + e];

            short8 af0[2], af1[2];
#pragma unroll
            for (int af = 0; af < 2; ++af) {
                float ex0[8], ex1[8];
#pragma unroll
                for (int e = 0; e < 8; ++e) {
                    float sd = cix[af] * cv[e].x;
                    sd = fmaf(ciy[af], cv[e].y, sd);
                    sd = fmaf(ciz[af], cv[e].z, sd);
                    float d2 = (ri2[af] + cv[e].w) - 2.f * sd;
                    ex0[e] = exp2f(d2 * ch0);
                    ex1[e] = exp2f(d2 * ch1);
                }
                union { unsigned u[4]; short8 s8; } pk0, pk1;
#pragma unroll
                for (int p = 0; p < 4; ++p) {
                    asm("v_cvt_pk_bf16_f32 %0, %1, %2"
                        : "=v"(pk0.u[p]) : "v"(ex0[2 * p]), "v"(ex0[2 * p + 1]));
                    asm("v_cvt_pk_bf16_f32 %0, %1, %2"
                        : "=v"(pk1.u[p]) : "v"(ex1[2 * p]), "v"(ex1[2 * p + 1]));
                }
                af0[af] = pk0.s8;
                af1[af] = pk1.s8;
                accd0[af] = __builtin_amdgcn_mfma_f32_16x16x32_bf16(af0[af], ones, accd0[af], 0, 0, 0);
                accd1[af] = __builtin_amdgcn_mfma_f32_16x16x32_bf16(af1[af], ones, accd1[af], 0, 0, 0);
            }
            int jb = kk * 4 + g;
#pragma unroll
            for (int nn = 0; nn < 4; ++nn) {
                int c = nn * 16 + lr;
                short8 bf0 = *(const short8*)(buf + c * 128 + ((jb ^ (c & 7)) << 4));
                int c2 = 64 + nn * 16 + lr;
                short8 bf1 = *(const short8*)(buf + c2 * 128 + ((jb ^ (c2 & 7)) << 4));
#pragma unroll
                for (int af = 0; af < 2; ++af) {
                    acc0[af][nn] = __builtin_amdgcn_mfma_f32_16x16x32_bf16(af0[af], bf0, acc0[af][nn], 0, 0, 0);
                    acc1[af][nn] = __builtin_amdgcn_mfma_f32_16x16x32_bf16(af1[af], bf1, acc1[af][nn], 0, 0, 0);
                }
            }
        }
    }

    size_t obase = ((size_t)sj * R_ + (size_t)b * N_) * 256;
#pragma unroll
    for (int af = 0; af < 2; ++af) {
#pragma unroll
        for (int r = 0; r < 4; ++r) {
            int row = i_base + af * 64 + w * 16 + g * 4 + r;
            size_t rb = obase + (size_t)row * 256 + hc + lr;
#pragma unroll
            for (int nn = 0; nn < 4; ++nn) {
                opart[rb + nn * 16] = f2bf(acc0[af][nn][r]);
                opart[rb + 64 + nn * 16] = f2bf(acc1[af][nn][r]);
            }
            if (lr == 0) {
                dpart[(sj * R_ + b * N_ + row) * 4 + h0] = accd0[af][r];
                dpart[(sj * R_ + b * N_ + row) * 4 + h0 + 1] = accd1[af][r];
            }
        }
    }
}

// ---------------------------------------------------------------------------
extern "C" void kernel_launch(void* const* d_in, const int* in_sizes, int n_in,
                              void* d_out, int out_size, void* d_ws, size_t ws_size,
                              hipStream_t stream) {
    const float* lat    = (const float*)d_in[0];
    const float* xc     = (const float*)d_in[1];
    const float* emb    = (const float*)d_in[2];
    const float* in_W   = (const float*)d_in[3];
    const float* in_b   = (const float*)d_in[4];
    const float* val_W  = (const float*)d_in[5];
    const float* val_b  = (const float*)d_in[6];
    const float* attn_W = (const float*)d_in[7];
    const float* attn_b = (const float*)d_in[8];
    const float* ln1_g  = (const float*)d_in[9];
    const float* ln1_b  = (const float*)d_in[10];
    const float* ln2_g  = (const float*)d_in[11];
    const float* ln2_b  = (const float*)d_in[12];
    const float* ffn_W1 = (const float*)d_in[13];
    const float* ffn_b1 = (const float*)d_in[14];
    const float* ffn_W2 = (const float*)d_in[15];
    const float* ffn_b2 = (const float*)d_in[16];
    const float* out_W1 = (const float*)d_in[17];
    const float* out_b1 = (const float*)d_in[18];
    const float* out_W2 = (const float*)d_in[19];
    const float* out_b2 = (const float*)d_in[20];

    char* W = (char*)d_ws;
    float*  feats  = (float*)W;                                // 8 MB
    ushort* featsb = (ushort*)(W + (8u << 20));                // 4 MB
    ushort* Vt     = (ushort*)(W + (12u << 20));               // 4 MB
    ushort* wp     = (ushort*)(W + (16u << 20));               // 3.2 MB
    ushort* opart  = (ushort*)(W + (20u << 20));               // 16 MB [4][R][256]
    float*  dpart  = (float*)(W + (36u << 20));                // 512 KB [4][R][4]
    ushort* Wvt  = wp;
    ushort* Wat  = wp + 262144;
    ushort* W1t  = wp + 524288;
    ushort* W2t  = wp + 1048576;
    ushort* Wo1t = wp + 1572864;

    pack_weights<<<6400, 256, 0, stream>>>(val_W, attn_W, ffn_W1, ffn_W2, out_W1, wp);
    input_mlp<<<R_ / 8, 256, 0, stream>>>(xc, emb, lat, in_W, in_b, feats, featsb);

    for (int l = 0; l < LAYERS_; ++l) {
        gemmM<256, 256, 3><<<dim3(R_ / 16, 1), 256, 0, stream>>>(
            featsb, Wvt + l * 65536, val_b + l * 256,
            nullptr, nullptr, nullptr, Vt, nullptr);
        attn_mfma<<<512, 256, 0, stream>>>(xc, Vt, opart, dpart);
        gemmA<<<R_ / 16, 256, 0, stream>>>(
            opart, dpart, Wat + l * 65536, attn_b + l * 256,
            feats, ln1_g + l * 256, ln1_b + l * 256, featsb, feats);
        gemmF<<<R_ / 16, 256, 0, stream>>>(
            featsb, W1t + l * 131072, ffn_b1 + l * 512,
            W2t + l * 131072, ffn_b2 + l * 256,
            feats, ln2_g + l * 256, ln2_b + l * 256, featsb, feats);
    }

    gemmM<256, 256, 4><<<dim3(R_ / 16, 1), 256, 0, stream>>>(
        featsb, Wo1t, out_b1, out_W2, out_b2, nullptr, nullptr, (float*)d_out);
}

// Round 9
// 283.905 us; speedup vs baseline: 1.1051x; 1.1051x over previous
//
#include <hip/hip_runtime.h>

#define B_ 4
#define N_ 2048
#define R_ (B_ * N_)      // 8192 rows
#define HID_ 256
#define EMB_ 64
#define IN_DIM_ 70
#define H_ 4
#define HEAD_ 64
#define FFN_ 512
#define LAYERS_ 4

typedef __attribute__((ext_vector_type(8))) short short8;
typedef __attribute__((ext_vector_type(4))) float f32x4;
typedef unsigned short ushort;

static __device__ __forceinline__ ushort f2bf(float f) {
    unsigned u = __builtin_bit_cast(unsigned, f);
    u += 0x7fffu + ((u >> 16) & 1u);   // RNE
    return (ushort)(u >> 16);
}
static __device__ __forceinline__ float bf2f(ushort u) {
    unsigned x = ((unsigned)u) << 16;
    return __builtin_bit_cast(float, x);
}

#define GLOAD_LDS16(g, l)                                              \
    __builtin_amdgcn_global_load_lds(                                  \
        (const __attribute__((address_space(1))) void*)(g),            \
        (__attribute__((address_space(3))) void*)(l), 16, 0, 0)

// ---------------------------------------------------------------------------
// Pack all weights to bf16, transposed [c][k] layout, in one kernel.
// ---------------------------------------------------------------------------
__global__ __launch_bounds__(256) void pack_weights(const float* __restrict__ valW,
                                                    const float* __restrict__ attnW,
                                                    const float* __restrict__ ffnW1,
                                                    const float* __restrict__ ffnW2,
                                                    const float* __restrict__ outW1,
                                                    ushort* __restrict__ wp) {
    int idx = blockIdx.x * 256 + threadIdx.x;
    float v;
    if (idx < 262144) {
        int l = idx >> 16, c = (idx >> 8) & 255, k = idx & 255;
        v = valW[((l * 4 + (c >> 6)) * 256 + k) * 64 + (c & 63)];
    } else if (idx < 524288) {
        int i2 = idx - 262144;
        int l = i2 >> 16, c = (i2 >> 8) & 255, k = i2 & 255;
        v = attnW[l * 65536 + k * 256 + c];
    } else if (idx < 1048576) {
        int i2 = idx - 524288;
        int l = i2 >> 17, c = (i2 >> 8) & 511, k = i2 & 255;
        v = ffnW1[l * 131072 + k * 512 + c];
    } else if (idx < 1572864) {
        int i2 = idx - 1048576;
        int l = i2 >> 17, c = (i2 >> 9) & 255, k = i2 & 511;
        v = ffnW2[l * 131072 + k * 256 + c];
    } else {
        int i2 = idx - 1572864;
        int c = i2 >> 8, k = i2 & 255;
        v = outW1[k * 256 + c];
    }
    wp[idx] = f2bf(v);
}

// ---------------------------------------------------------------------------
// Input MLP: feats = relu(concat @ in_W + in_b); dual write fp32 + bf16
// ---------------------------------------------------------------------------
__global__ __launch_bounds__(256) void input_mlp(const float* __restrict__ xc,
                                                 const float* __restrict__ emb,
                                                 const float* __restrict__ lat,
                                                 const float* __restrict__ W,
                                                 const float* __restrict__ b,
                                                 float* __restrict__ feats,
                                                 ushort* __restrict__ featsb) {
    __shared__ float xr[8][IN_DIM_ + 2];
    int t = threadIdx.x;
    int row0 = blockIdx.x * 8;
    for (int idx = t; idx < 8 * IN_DIM_; idx += 256) {
        int r = idx / IN_DIM_, f = idx % IN_DIM_;
        int rr = row0 + r;
        float v;
        if (f < 3)       v = xc[rr * 3 + f];
        else if (f < 67) v = emb[rr * EMB_ + (f - 3)];
        else             v = lat[rr * 3 + (f - 67)];
        xr[r][f] = v;
    }
    __syncthreads();
    float acc[8] = {0.f, 0.f, 0.f, 0.f, 0.f, 0.f, 0.f, 0.f};
    for (int f = 0; f < IN_DIM_; ++f) {
        float w = W[f * HID_ + t];
#pragma unroll
        for (int r = 0; r < 8; ++r) acc[r] += xr[r][f] * w;
    }
    float bb = b[t];
#pragma unroll
    for (int r = 0; r < 8; ++r) {
        float v = fmaxf(acc[r] + bb, 0.f);
        feats[(row0 + r) * HID_ + t] = v;
        featsb[(row0 + r) * HID_ + t] = f2bf(v);
    }
}

// ---------------------------------------------------------------------------
// ebuild: E[h][b][i][j] = exp2(-d2(b,i,j) * inv_h * log2e) as bf16, built
// ONCE (A depends only on coords). d2 computed once, shared by all 4 heads.
// Block: 256 j x 64 i tile; lane owns 4 consecutive j (held in regs),
// ig=t>>6 sweeps 16 i. Stores: uint2 (4 bf16) per (i,h), lanes contiguous.
// Grid (8, 32, B). Write-BW bound (~134 MB).
// ---------------------------------------------------------------------------
__global__ __launch_bounds__(256) void ebuild(const float* __restrict__ xc,
                                              ushort* __restrict__ E) {
    __shared__ float4 civ[64];
    __shared__ float4 cjv[256];
    int t = threadIdx.x;
    int jb = blockIdx.x;      // j-tile of 256
    int ibl = blockIdx.y;     // i-tile of 64
    int b = blockIdx.z;
    const float* xb = xc + (size_t)b * N_ * 3;
    if (t < 64) {
        const float* p = &xb[(ibl * 64 + t) * 3];
        float x = p[0], y = p[1], z = p[2];
        civ[t] = make_float4(x, y, z, x * x + y * y + z * z);
    }
    {
        const float* p = &xb[(jb * 256 + t) * 3];
        float x = p[0], y = p[1], z = p[2];
        cjv[t] = make_float4(x, y, z, x * x + y * y + z * z);
    }
    __syncthreads();
    int lane = t & 63, ig = t >> 6;
    float4 cj0 = cjv[lane * 4 + 0];
    float4 cj1 = cjv[lane * 4 + 1];
    float4 cj2 = cjv[lane * 4 + 2];
    float4 cj3 = cjv[lane * 4 + 3];
    const float ch0 = -4.f * 1.44269504088896f;   // head0: inv=4
    size_t jcol = (size_t)jb * 256 + lane * 4;
    ushort* Ebase = E + ((size_t)b * 2048 + ibl * 64) * 2048 + jcol;

#pragma unroll 4
    for (int r = 0; r < 16; ++r) {
        int i = ig * 16 + r;
        float4 ci = civ[i];
        float d0 = (ci.w + cj0.w) - 2.f * (ci.x * cj0.x + ci.y * cj0.y + ci.z * cj0.z);
        float d1 = (ci.w + cj1.w) - 2.f * (ci.x * cj1.x + ci.y * cj1.y + ci.z * cj1.z);
        float d2 = (ci.w + cj2.w) - 2.f * (ci.x * cj2.x + ci.y * cj2.y + ci.z * cj2.z);
        float d3 = (ci.w + cj3.w) - 2.f * (ci.x * cj3.x + ci.y * cj3.y + ci.z * cj3.z);
        float ch = ch0;
#pragma unroll
        for (int h = 0; h < 4; ++h) {
            float e0 = exp2f(d0 * ch);
            float e1 = exp2f(d1 * ch);
            float e2 = exp2f(d2 * ch);
            float e3 = exp2f(d3 * ch);
            unsigned u0, u1;
            asm("v_cvt_pk_bf16_f32 %0, %1, %2" : "=v"(u0) : "v"(e0), "v"(e1));
            asm("v_cvt_pk_bf16_f32 %0, %1, %2" : "=v"(u1) : "v"(e2), "v"(e3));
            uint2 val; val.x = u0; val.y = u1;
            *(uint2*)(Ebase + (size_t)h * 4 * 2048 * 2048 + (size_t)i * 2048) = val;
            ch *= 0.25f;   // next lengthscale: inv/4
        }
    }
}

// ---------------------------------------------------------------------------
// pv_gemm: att[b, i, h*64+d] = (E[h,b,i,:] @ V[b,:,h-cols]) * 1/rowsum(E).
// Standard MFMA GEMM, KD=2048. Block = 4 waves x 16 rows = 64 i x 64 cols
// (one head). Rowsum via ones-MFMA on staged A-frags (no extra buffer).
// Grid 512, XCD-decoded: 32 i-blocks of one (b,h) per XCD-slice -> 256KB
// V-slice L2-hot. E streams from L3 (128 MiB resident).
// ---------------------------------------------------------------------------
__global__ __launch_bounds__(256, 2) void pv_gemm(const ushort* __restrict__ E,
                                                  const ushort* __restrict__ Vt,
                                                  ushort* __restrict__ attb) {
    __shared__ __align__(16) char lds[32768];   // [2] x (A 8KB + B 8KB)
    int t = threadIdx.x;
    int l = t & 63, w = t >> 6;
    int lr = l & 15, g = l >> 4;

    int f = blockIdx.x;                 // 512 blocks
    int xcd = f & 7, s = f >> 3;        // s: 0..63
    int combo = xcd * 2 + (s >> 5);     // 0..15
    int ib = s & 31;                    // 32 i-blocks of 64 rows
    int b = combo & 3, h = combo >> 2;
    int i_base = ib * 64;
    int hc = h * 64;

    const ushort* Eb = E + (size_t)(h * 4 + b) * 2048 * 2048;
    int slot = t & 7, trow = t >> 3;    // trow 0..31

    const ushort* srcA[2];
    const ushort* srcB[2];
#pragma unroll
    for (int q = 0; q < 2; ++q) {
        int arow = q * 32 + trow;
        srcA[q] = Eb + (size_t)(i_base + arow) * 2048 + ((slot ^ (arow & 7)) << 3);
        int cl = q * 32 + trow;
        srcB[q] = Vt + (size_t)(b * 256 + hc + cl) * 2048 + ((slot ^ (cl & 7)) << 3);
    }
    auto STAGE = [&](int buf) {
#pragma unroll
        for (int q = 0; q < 2; ++q)
            GLOAD_LDS16(srcA[q], lds + buf * 16384 + q * 4096 + t * 16);
#pragma unroll
        for (int q = 0; q < 2; ++q)
            GLOAD_LDS16(srcB[q], lds + buf * 16384 + 8192 + q * 4096 + t * 16);
#pragma unroll
        for (int q = 0; q < 2; ++q) { srcA[q] += 64; srcB[q] += 64; }
    };

    f32x4 acc[4] = {};
    f32x4 accd = {};
    short8 ones = {0x3F80, 0x3F80, 0x3F80, 0x3F80, 0x3F80, 0x3F80, 0x3F80, 0x3F80};

    int arow = w * 16 + lr;
    int aoff = arow * 128;
    int sw_a = (arow & 7) << 4;         // == (lr&7)<<4

    STAGE(0);
    for (int c = 0; c < 32; ++c) {
        __syncthreads();
        if (c + 1 < 32) STAGE((c + 1) & 1);
        const char* As = lds + (c & 1) * 16384;
        const char* Bs = As + 8192;

        short8 a0 = *(const short8*)(As + aoff + ((g * 16) ^ sw_a));
        short8 a1 = *(const short8*)(As + aoff + ((64 + g * 16) ^ sw_a));
        accd = __builtin_amdgcn_mfma_f32_16x16x32_bf16(a0, ones, accd, 0, 0, 0);
        accd = __builtin_amdgcn_mfma_f32_16x16x32_bf16(a1, ones, accd, 0, 0, 0);
#pragma unroll
        for (int n = 0; n < 4; ++n) {
            int cc = n * 16 + lr;
            const char* cb = Bs + cc * 128;
            int sw = (cc & 7) << 4;
            short8 b0 = *(const short8*)(cb + ((g * 16) ^ sw));
            short8 b1 = *(const short8*)(cb + ((64 + g * 16) ^ sw));
            acc[n] = __builtin_amdgcn_mfma_f32_16x16x32_bf16(a0, b0, acc[n], 0, 0, 0);
            acc[n] = __builtin_amdgcn_mfma_f32_16x16x32_bf16(a1, b1, acc[n], 0, 0, 0);
        }
    }

#pragma unroll
    for (int r = 0; r < 4; ++r) {
        float invd = 1.f / (accd[r] + 1e-8f);
        int row = i_base + w * 16 + g * 4 + r;
        size_t rb = ((size_t)b * N_ + row) * 256 + hc + lr;
#pragma unroll
        for (int n = 0; n < 4; ++n)
            attb[rb + n * 16] = f2bf(acc[n][r] * invd);
    }
}

// ---------------------------------------------------------------------------
// MFMA bf16 GEMM, double-buffered K-loop.
// MODE 2: +bias,+resid,LN -> fp32 + bf16 (attn-proj+LN1)
// MODE 3: +bias -> transposed bf16 Vt[c][n]  (V-proj)
// MODE 4: +bias, relu, then @W2+b2 -> fp32 d_out (final)
// ---------------------------------------------------------------------------
template <int KD, int COLS, int MODE>
__global__ __launch_bounds__(256) void gemmM(const ushort* __restrict__ A,
                                             const ushort* __restrict__ Bt,
                                             const float* __restrict__ bias,
                                             const float* __restrict__ resid,
                                             const float* __restrict__ lng,
                                             const float* __restrict__ lnb,
                                             ushort* __restrict__ outb,
                                             float* __restrict__ outf) {
    __shared__ __align__(16) char lds[69632];   // As[2]:4KB | Ws[2]:64KB
    int t = threadIdx.x;
    int l = t & 63, w = t >> 6;
    int lr = l & 15, g = l >> 4;
    int row0 = blockIdx.x * 16;
    int cbase = blockIdx.y * 256;
    f32x4 acc[4] = {};

    const ushort* srcA = A + (size_t)(row0 + (t >> 3)) * KD + (((t & 7) ^ ((t >> 3) & 7)) << 3);
    const ushort* srcB[8];
#pragma unroll
    for (int q = 0; q < 8; ++q) {
        int cl = q * 32 + (t >> 3);
        srcB[q] = Bt + (size_t)(cbase + cl) * KD + (((t & 7) ^ (cl & 7)) << 3);
    }

    auto STAGE = [&](int buf) {
        if (t < 128) GLOAD_LDS16(srcA, lds + buf * 2048 + t * 16);
#pragma unroll
        for (int q = 0; q < 8; ++q)
            GLOAD_LDS16(srcB[q], lds + 4096 + buf * 32768 + q * 4096 + t * 16);
        srcA += 64;
#pragma unroll
        for (int q = 0; q < 8; ++q) srcB[q] += 64;
    };

    int sw_a = (lr & 7) << 4;
    int aoff = lr * 128;
    constexpr int CH = KD / 64;

    STAGE(0);
#pragma unroll
    for (int c = 0; c < CH; ++c) {
        __syncthreads();
        if (c + 1 < CH) STAGE((c + 1) & 1);
        const char* As = lds + (c & 1) * 2048;
        const char* Ws = lds + 4096 + (c & 1) * 32768;

        short8 a0 = *(const short8*)(As + aoff + ((g * 16) ^ sw_a));
        short8 a1 = *(const short8*)(As + aoff + ((64 + g * 16) ^ sw_a));
#pragma unroll
        for (int n = 0; n < 4; ++n) {
            int cc = w * 64 + n * 16 + lr;
            const char* cb = Ws + cc * 128;
            int sw = (cc & 7) << 4;
            short8 b0 = *(const short8*)(cb + ((g * 16) ^ sw));
            short8 b1 = *(const short8*)(cb + ((64 + g * 16) ^ sw));
            acc[n] = __builtin_amdgcn_mfma_f32_16x16x32_bf16(a0, b0, acc[n], 0, 0, 0);
            acc[n] = __builtin_amdgcn_mfma_f32_16x16x32_bf16(a1, b1, acc[n], 0, 0, 0);
        }
    }
    __syncthreads();

    if constexpr (MODE == 2) {
        float* red1 = (float*)lds;
        float* red2 = (float*)(lds + 512);
        float vals[4][4];
        float s1[4] = {0.f, 0.f, 0.f, 0.f}, s2[4] = {0.f, 0.f, 0.f, 0.f};
#pragma unroll
        for (int n = 0; n < 4; ++n) {
            int c = w * 64 + n * 16 + lr;
            float bi = bias[c];
#pragma unroll
            for (int r = 0; r < 4; ++r) {
                int row = row0 + g * 4 + r;
                float v = acc[n][r] + bi + resid[(size_t)row * 256 + c];
                vals[n][r] = v;
                s1[r] += v;
                s2[r] += v * v;
            }
        }
#pragma unroll
        for (int off = 1; off < 16; off <<= 1) {
#pragma unroll
            for (int r = 0; r < 4; ++r) {
                s1[r] += __shfl_xor(s1[r], off, 64);
                s2[r] += __shfl_xor(s2[r], off, 64);
            }
        }
        if (lr == 0) {
#pragma unroll
            for (int r = 0; r < 4; ++r) {
                red1[(g * 4 + r) * 4 + w] = s1[r];
                red2[(g * 4 + r) * 4 + w] = s2[r];
            }
        }
        __syncthreads();
#pragma unroll
        for (int n = 0; n < 4; ++n) {
            int c = w * 64 + n * 16 + lr;
            float gg = lng[c], bb = lnb[c];
#pragma unroll
            for (int r = 0; r < 4; ++r) {
                int rr = g * 4 + r;
                float m1 = red1[rr * 4] + red1[rr * 4 + 1] + red1[rr * 4 + 2] + red1[rr * 4 + 3];
                float m2 = red2[rr * 4] + red2[rr * 4 + 1] + red2[rr * 4 + 2] + red2[rr * 4 + 3];
                float mu = m1 * (1.f / 256.f);
                float var = m2 * (1.f / 256.f) - mu * mu;
                float rstd = rsqrtf(var + 1e-5f);
                int row = row0 + rr;
                float o = (vals[n][r] - mu) * rstd * gg + bb;
                outf[(size_t)row * 256 + c] = o;
                outb[(size_t)row * 256 + c] = f2bf(o);
            }
        }
    } else if constexpr (MODE == 3) {
        ushort(*Ts)[24] = (ushort(*)[24])lds;   // [256][24]
#pragma unroll
        for (int n = 0; n < 4; ++n) {
            int c = w * 64 + n * 16 + lr;
            float bi = bias[c];
#pragma unroll
            for (int r = 0; r < 4; ++r)
                Ts[c][g * 4 + r] = f2bf(acc[n][r] + bi);
        }
        __syncthreads();
        {
            int c = t;
            int b = row0 >> 11;
            int n0 = row0 & 2047;
            ushort* dst = outb + ((size_t)(b * 256 + c)) * 2048 + n0;
            uint4 v0 = *(uint4*)&Ts[c][0];
            uint4 v1 = *(uint4*)&Ts[c][8];
            *(uint4*)dst = v0;
            *(uint4*)(dst + 8) = v1;
        }
    } else {  // MODE 4
        const float* W2 = resid;    // [256][3]
        const float* b2 = lng;      // [3]
        ushort(*Ts)[264] = (ushort(*)[264])lds;  // [16][264]
#pragma unroll
        for (int n = 0; n < 4; ++n) {
            int c = w * 64 + n * 16 + lr;
            float bi = bias[c];
#pragma unroll
            for (int r = 0; r < 4; ++r)
                Ts[g * 4 + r][c] = f2bf(fmaxf(acc[n][r] + bi, 0.f));
        }
        __syncthreads();
        int row = t >> 4, s = t & 15;
        float p0 = 0.f, p1 = 0.f, p2 = 0.f;
#pragma unroll
        for (int e = 0; e < 16; ++e) {
            float x = bf2f(Ts[row][s * 16 + e]);
            const float* wr = &W2[(s * 16 + e) * 3];
            p0 += x * wr[0];
            p1 += x * wr[1];
            p2 += x * wr[2];
        }
#pragma unroll
        for (int off = 1; off < 16; off <<= 1) {
            p0 += __shfl_xor(p0, off, 64);
            p1 += __shfl_xor(p1, off, 64);
            p2 += __shfl_xor(p2, off, 64);
        }
        if (s == 0) {
            int gr = row0 + row;
            outf[gr * 3 + 0] = p0 + b2[0];
            outf[gr * 3 + 1] = p1 + b2[1];
            outf[gr * 3 + 2] = p2 + b2[2];
        }
    }
}

// ---------------------------------------------------------------------------
// gemmF: fused FFN1 + ReLU + FFN2 + LN2 (unchanged).
// ---------------------------------------------------------------------------
__global__ __launch_bounds__(256) void gemmF(const ushort* __restrict__ A,
                                             const ushort* __restrict__ W1t,
                                             const float* __restrict__ b1,
                                             const ushort* __restrict__ W2t,
                                             const float* __restrict__ b2,
                                             const float* __restrict__ resid,
                                             const float* __restrict__ lng,
                                             const float* __restrict__ lnb,
                                             ushort* __restrict__ outb,
                                             float* __restrict__ outf) {
    __shared__ __align__(16) char lds[57344];
    char* Asp = lds;
    char* Wsp = lds + 8192;
    char* hidp = lds + 40960;

    int t = threadIdx.x;
    int l = t & 63, w = t >> 6;
    int lr = l & 15, g = l >> 4;
    int row0 = blockIdx.x * 16;
    int sw_a = (lr & 7) << 4;

#pragma unroll
    for (int shot = 0; shot < 2; ++shot) {
        int si = shot * 256 + t;
        int row = si >> 5, sl = si & 31;
        const ushort* src = A + (size_t)(row0 + row) * 256 + ((sl ^ (row & 7)) << 3);
        GLOAD_LDS16(src, Asp + si * 16);
    }

    uint4 wr0, wr1, wr2, wr3, wr4, wr5, wr6, wr7;
    auto WLOAD1 = [&](int ch, int c) {
        const ushort* base = W1t + c * 64;
#pragma unroll
        for (int q = 0; q < 8; ++q) {
            int cl = ch * 256 + q * 32 + (t >> 3);
            const uint4* s = (const uint4*)(base + (size_t)cl * 256 + (((t & 7) ^ (cl & 7)) << 3));
            uint4 v = *s;
            if (q == 0) wr0 = v; else if (q == 1) wr1 = v; else if (q == 2) wr2 = v;
            else if (q == 3) wr3 = v; else if (q == 4) wr4 = v; else if (q == 5) wr5 = v;
            else if (q == 6) wr6 = v; else wr7 = v;
        }
    };
    auto WLOAD2 = [&](int c) {
        const ushort* base = W2t + c * 64;
#pragma unroll
        for (int q = 0; q < 8; ++q) {
            int cl = q * 32 + (t >> 3);
            const uint4* s = (const uint4*)(base + (size_t)cl * 512 + (((t & 7) ^ (cl & 7)) << 3));
            uint4 v = *s;
            if (q == 0) wr0 = v; else if (q == 1) wr1 = v; else if (q == 2) wr2 = v;
            else if (q == 3) wr3 = v; else if (q == 4) wr4 = v; else if (q == 5) wr5 = v;
            else if (q == 6) wr6 = v; else wr7 = v;
        }
    };
    auto WSTORE = [&]() {
        *(uint4*)(Wsp + 0 * 4096 + t * 16) = wr0;
        *(uint4*)(Wsp + 1 * 4096 + t * 16) = wr1;
        *(uint4*)(Wsp + 2 * 4096 + t * 16) = wr2;
        *(uint4*)(Wsp + 3 * 4096 + t * 16) = wr3;
        *(uint4*)(Wsp + 4 * 4096 + t * 16) = wr4;
        *(uint4*)(Wsp + 5 * 4096 + t * 16) = wr5;
        *(uint4*)(Wsp + 6 * 4096 + t * 16) = wr6;
        *(uint4*)(Wsp + 7 * 4096 + t * 16) = wr7;
    };

    WLOAD1(0, 0);

#pragma unroll
    for (int ch = 0; ch < 2; ++ch) {
        f32x4 acc[4] = {};
#pragma unroll
        for (int c = 0; c < 4; ++c) {
            __syncthreads();
            WSTORE();
            __syncthreads();
            if (c < 3) WLOAD1(ch, c + 1);
            else if (ch == 0) WLOAD1(1, 0);
            else WLOAD2(0);

            short8 a0 = *(const short8*)(Asp + lr * 512 + ((c * 128 + g * 16) ^ sw_a));
            short8 a1 = *(const short8*)(Asp + lr * 512 + ((c * 128 + 64 + g * 16) ^ sw_a));
#pragma unroll
            for (int n = 0; n < 4; ++n) {
                int cc = w * 64 + n * 16 + lr;
                const char* cb = Wsp + cc * 128;
                int sw = (cc & 7) << 4;
                short8 b0 = *(const short8*)(cb + ((g * 16) ^ sw));
                short8 b1 = *(const short8*)(cb + ((64 + g * 16) ^ sw));
                acc[n] = __builtin_amdgcn_mfma_f32_16x16x32_bf16(a0, b0, acc[n], 0, 0, 0);
                acc[n] = __builtin_amdgcn_mfma_f32_16x16x32_bf16(a1, b1, acc[n], 0, 0, 0);
            }
        }
#pragma unroll
        for (int n = 0; n < 4; ++n) {
            int c = w * 64 + n * 16 + lr;
            float bi = b1[ch * 256 + c];
#pragma unroll
            for (int r = 0; r < 4; ++r) {
                int rw = g * 4 + r;
                float v = fmaxf(acc[n][r] + bi, 0.f);
                int byte = rw * 1024 + (((ch * 256 + c) * 2) ^ ((rw & 7) << 4));
                *(ushort*)(hidp + byte) = f2bf(v);
            }
        }
    }

    f32x4 acc2[4] = {};
#pragma unroll
    for (int c = 0; c < 8; ++c) {
        __syncthreads();
        WSTORE();
        __syncthreads();
        if (c < 7) WLOAD2(c + 1);

        short8 a0 = *(const short8*)(hidp + lr * 1024 + ((c * 128 + g * 16) ^ sw_a));
        short8 a1 = *(const short8*)(hidp + lr * 1024 + ((c * 128 + 64 + g * 16) ^ sw_a));
#pragma unroll
        for (int n = 0; n < 4; ++n) {
            int cc = w * 64 + n * 16 + lr;
            const char* cb = Wsp + cc * 128;
            int sw = (cc & 7) << 4;
            short8 b0 = *(const short8*)(cb + ((g * 16) ^ sw));
            short8 b1 = *(const short8*)(cb + ((64 + g * 16) ^ sw));
            acc2[n] = __builtin_amdgcn_mfma_f32_16x16x32_bf16(a0, b0, acc2[n], 0, 0, 0);
            acc2[n] = __builtin_amdgcn_mfma_f32_16x16x32_bf16(a1, b1, acc2[n], 0, 0, 0);
        }
    }
    __syncthreads();

    float* red1 = (float*)lds;
    float* red2 = (float*)(lds + 512);
    float vals[4][4];
    float s1[4] = {0.f, 0.f, 0.f, 0.f}, s2[4] = {0.f, 0.f, 0.f, 0.f};
#pragma unroll
    for (int n = 0; n < 4; ++n) {
        int c = w * 64 + n * 16 + lr;
        float bi = b2[c];
#pragma unroll
        for (int r = 0; r < 4; ++r) {
            int row = row0 + g * 4 + r;
            float v = acc2[n][r] + bi + resid[(size_t)row * 256 + c];
            vals[n][r] = v;
            s1[r] += v;
            s2[r] += v * v;
        }
    }
#pragma unroll
    for (int off = 1; off < 16; off <<= 1) {
#pragma unroll
        for (int r = 0; r < 4; ++r) {
            s1[r] += __shfl_xor(s1[r], off, 64);
            s2[r] += __shfl_xor(s2[r], off, 64);
        }
    }
    if (lr == 0) {
#pragma unroll
        for (int r = 0; r < 4; ++r) {
            red1[(g * 4 + r) * 4 + w] = s1[r];
            red2[(g * 4 + r) * 4 + w] = s2[r];
        }
    }
    __syncthreads();
#pragma unroll
    for (int n = 0; n < 4; ++n) {
        int c = w * 64 + n * 16 + lr;
        float gg = lng[c], bb = lnb[c];
#pragma unroll
        for (int r = 0; r < 4; ++r) {
            int rr = g * 4 + r;
            float m1 = red1[rr * 4] + red1[rr * 4 + 1] + red1[rr * 4 + 2] + red1[rr * 4 + 3];
            float m2 = red2[rr * 4] + red2[rr * 4 + 1] + red2[rr * 4 + 2] + red2[rr * 4 + 3];
            float mu = m1 * (1.f / 256.f);
            float var = m2 * (1.f / 256.f) - mu * mu;
            float rstd = rsqrtf(var + 1e-5f);
            int row = row0 + rr;
            float o = (vals[n][r] - mu) * rstd * gg + bb;
            outf[(size_t)row * 256 + c] = o;
            outb[(size_t)row * 256 + c] = f2bf(o);
        }
    }
}

// ---------------------------------------------------------------------------
extern "C" void kernel_launch(void* const* d_in, const int* in_sizes, int n_in,
                              void* d_out, int out_size, void* d_ws, size_t ws_size,
                              hipStream_t stream) {
    const float* lat    = (const float*)d_in[0];
    const float* xc     = (const float*)d_in[1];
    const float* emb    = (const float*)d_in[2];
    const float* in_W   = (const float*)d_in[3];
    const float* in_b   = (const float*)d_in[4];
    const float* val_W  = (const float*)d_in[5];
    const float* val_b  = (const float*)d_in[6];
    const float* attn_W = (const float*)d_in[7];
    const float* attn_b = (const float*)d_in[8];
    const float* ln1_g  = (const float*)d_in[9];
    const float* ln1_b  = (const float*)d_in[10];
    const float* ln2_g  = (const float*)d_in[11];
    const float* ln2_b  = (const float*)d_in[12];
    const float* ffn_W1 = (const float*)d_in[13];
    const float* ffn_b1 = (const float*)d_in[14];
    const float* ffn_W2 = (const float*)d_in[15];
    const float* ffn_b2 = (const float*)d_in[16];
    const float* out_W1 = (const float*)d_in[17];
    const float* out_b1 = (const float*)d_in[18];
    const float* out_W2 = (const float*)d_in[19];
    const float* out_b2 = (const float*)d_in[20];

    char* W = (char*)d_ws;
    float*  feats  = (float*)W;                                // 8 MB
    ushort* featsb = (ushort*)(W + (8u << 20));                // 4 MB
    ushort* attb   = (ushort*)(W + (12u << 20));               // 4 MB
    ushort* Vt     = (ushort*)(W + (16u << 20));               // 4 MB
    ushort* wp     = (ushort*)(W + (20u << 20));               // 3.2 MB
    ushort* E      = (ushort*)(W + (24u << 20));               // 128 MiB [H][B][N][N]
    ushort* Wvt  = wp;
    ushort* Wat  = wp + 262144;
    ushort* W1t  = wp + 524288;
    ushort* W2t  = wp + 1048576;
    ushort* Wo1t = wp + 1572864;

    pack_weights<<<6400, 256, 0, stream>>>(val_W, attn_W, ffn_W1, ffn_W2, out_W1, wp);
    input_mlp<<<R_ / 8, 256, 0, stream>>>(xc, emb, lat, in_W, in_b, feats, featsb);
    ebuild<<<dim3(8, 32, B_), 256, 0, stream>>>(xc, E);

    for (int l = 0; l < LAYERS_; ++l) {
        gemmM<256, 256, 3><<<dim3(R_ / 16, 1), 256, 0, stream>>>(
            featsb, Wvt + l * 65536, val_b + l * 256,
            nullptr, nullptr, nullptr, Vt, nullptr);
        pv_gemm<<<512, 256, 0, stream>>>(E, Vt, attb);
        gemmM<256, 256, 2><<<dim3(R_ / 16, 1), 256, 0, stream>>>(
            attb, Wat + l * 65536, attn_b + l * 256,
            feats, ln1_g + l * 256, ln1_b + l * 256, featsb, feats);
        gemmF<<<R_ / 16, 256, 0, stream>>>(
            featsb, W1t + l * 131072, ffn_b1 + l * 512,
            W2t + l * 131072, ffn_b2 + l * 256,
            feats, ln2_g + l * 256, ln2_b + l * 256, featsb, feats);
    }

    gemmM<256, 256, 4><<<dim3(R_ / 16, 1), 256, 0, stream>>>(
        featsb, Wo1t, out_b1, out_W2, out_b2, nullptr, nullptr, (float*)d_out);
}

// Round 10
// 260.981 us; speedup vs baseline: 1.2022x; 1.0878x over previous
//
#include <hip/hip_runtime.h>

#define B_ 4
#define N_ 2048
#define R_ (B_ * N_)      // 8192 rows
#define HID_ 256
#define EMB_ 64
#define IN_DIM_ 70
#define H_ 4
#define HEAD_ 64
#define FFN_ 512
#define LAYERS_ 4

typedef __attribute__((ext_vector_type(8))) short short8;
typedef __attribute__((ext_vector_type(4))) float f32x4;
typedef unsigned short ushort;

static __device__ __forceinline__ ushort f2bf(float f) {
    unsigned u = __builtin_bit_cast(unsigned, f);
    u += 0x7fffu + ((u >> 16) & 1u);   // RNE
    return (ushort)(u >> 16);
}
static __device__ __forceinline__ float bf2f(ushort u) {
    unsigned x = ((unsigned)u) << 16;
    return __builtin_bit_cast(float, x);
}

#define GLOAD_LDS16(g, l)                                              \
    __builtin_amdgcn_global_load_lds(                                  \
        (const __attribute__((address_space(1))) void*)(g),            \
        (__attribute__((address_space(3))) void*)(l), 16, 0, 0)

// ---------------------------------------------------------------------------
// Pack all weights to bf16, transposed [c][k] layout, in one kernel.
// ---------------------------------------------------------------------------
__global__ __launch_bounds__(256) void pack_weights(const float* __restrict__ valW,
                                                    const float* __restrict__ attnW,
                                                    const float* __restrict__ ffnW1,
                                                    const float* __restrict__ ffnW2,
                                                    const float* __restrict__ outW1,
                                                    ushort* __restrict__ wp) {
    int idx = blockIdx.x * 256 + threadIdx.x;
    float v;
    if (idx < 262144) {
        int l = idx >> 16, c = (idx >> 8) & 255, k = idx & 255;
        v = valW[((l * 4 + (c >> 6)) * 256 + k) * 64 + (c & 63)];
    } else if (idx < 524288) {
        int i2 = idx - 262144;
        int l = i2 >> 16, c = (i2 >> 8) & 255, k = i2 & 255;
        v = attnW[l * 65536 + k * 256 + c];
    } else if (idx < 1048576) {
        int i2 = idx - 524288;
        int l = i2 >> 17, c = (i2 >> 8) & 511, k = i2 & 255;
        v = ffnW1[l * 131072 + k * 512 + c];
    } else if (idx < 1572864) {
        int i2 = idx - 1048576;
        int l = i2 >> 17, c = (i2 >> 9) & 255, k = i2 & 511;
        v = ffnW2[l * 131072 + k * 256 + c];
    } else {
        int i2 = idx - 1572864;
        int c = i2 >> 8, k = i2 & 255;
        v = outW1[k * 256 + c];
    }
    wp[idx] = f2bf(v);
}

// ---------------------------------------------------------------------------
// Input MLP: feats = relu(concat @ in_W + in_b); dual write fp32 + bf16
// ---------------------------------------------------------------------------
__global__ __launch_bounds__(256) void input_mlp(const float* __restrict__ xc,
                                                 const float* __restrict__ emb,
                                                 const float* __restrict__ lat,
                                                 const float* __restrict__ W,
                                                 const float* __restrict__ b,
                                                 float* __restrict__ feats,
                                                 ushort* __restrict__ featsb) {
    __shared__ float xr[8][IN_DIM_ + 2];
    int t = threadIdx.x;
    int row0 = blockIdx.x * 8;
    for (int idx = t; idx < 8 * IN_DIM_; idx += 256) {
        int r = idx / IN_DIM_, f = idx % IN_DIM_;
        int rr = row0 + r;
        float v;
        if (f < 3)       v = xc[rr * 3 + f];
        else if (f < 67) v = emb[rr * EMB_ + (f - 3)];
        else             v = lat[rr * 3 + (f - 67)];
        xr[r][f] = v;
    }
    __syncthreads();
    float acc[8] = {0.f, 0.f, 0.f, 0.f, 0.f, 0.f, 0.f, 0.f};
    for (int f = 0; f < IN_DIM_; ++f) {
        float w = W[f * HID_ + t];
#pragma unroll
        for (int r = 0; r < 8; ++r) acc[r] += xr[r][f] * w;
    }
    float bb = b[t];
#pragma unroll
    for (int r = 0; r < 8; ++r) {
        float v = fmaxf(acc[r] + bb, 0.f);
        feats[(row0 + r) * HID_ + t] = v;
        featsb[(row0 + r) * HID_ + t] = f2bf(v);
    }
}

// ---------------------------------------------------------------------------
// ebuild: E[h][b][i][j] bf16, built once. Lane owns 8 consecutive j (uint4
// 16B stores). Block: 512 j x 64 i. Grid (4, 32, B).
// ---------------------------------------------------------------------------
__global__ __launch_bounds__(256) void ebuild(const float* __restrict__ xc,
                                              ushort* __restrict__ E) {
    __shared__ float4 civ[64];
    __shared__ float4 cjv[512];
    int t = threadIdx.x;
    int jb = blockIdx.x;      // j-tile of 512
    int ibl = blockIdx.y;     // i-tile of 64
    int b = blockIdx.z;
    const float* xb = xc + (size_t)b * N_ * 3;
    if (t < 64) {
        const float* p = &xb[(ibl * 64 + t) * 3];
        float x = p[0], y = p[1], z = p[2];
        civ[t] = make_float4(x, y, z, x * x + y * y + z * z);
    }
#pragma unroll
    for (int s = 0; s < 2; ++s) {
        int j = s * 256 + t;
        const float* p = &xb[(jb * 512 + j) * 3];
        float x = p[0], y = p[1], z = p[2];
        cjv[j] = make_float4(x, y, z, x * x + y * y + z * z);
    }
    __syncthreads();
    int lane = t & 63, ig = t >> 6;
    float4 cj[8];
#pragma unroll
    for (int e = 0; e < 8; ++e) cj[e] = cjv[lane * 8 + e];
    const float ch0 = -4.f * 1.44269504088896f;   // head0: inv=4
    ushort* Ebase = E + ((size_t)b * 2048 + ibl * 64) * 2048 + (size_t)jb * 512 + lane * 8;

    for (int r = 0; r < 16; ++r) {
        int i = ig * 16 + r;
        float4 ci = civ[i];
        float d[8];
#pragma unroll
        for (int e = 0; e < 8; ++e)
            d[e] = (ci.w + cj[e].w) -
                   2.f * (ci.x * cj[e].x + ci.y * cj[e].y + ci.z * cj[e].z);
        float ch = ch0;
#pragma unroll
        for (int h = 0; h < 4; ++h) {
            float ex[8];
#pragma unroll
            for (int e = 0; e < 8; ++e) ex[e] = exp2f(d[e] * ch);
            union { unsigned u[4]; uint4 v; } pk;
#pragma unroll
            for (int q = 0; q < 4; ++q)
                asm("v_cvt_pk_bf16_f32 %0, %1, %2"
                    : "=v"(pk.u[q]) : "v"(ex[2 * q]), "v"(ex[2 * q + 1]));
            *(uint4*)(Ebase + (size_t)h * 4 * 2048 * 2048 + (size_t)i * 2048) = pk.v;
            ch *= 0.25f;
        }
    }
}

// ---------------------------------------------------------------------------
// pv_gemm: att[b,i,h*64+d] = (E[h,b,i,:] @ V) / rowsum(E). (unchanged R9)
// ---------------------------------------------------------------------------
__global__ __launch_bounds__(256, 2) void pv_gemm(const ushort* __restrict__ E,
                                                  const ushort* __restrict__ Vt,
                                                  ushort* __restrict__ attb) {
    __shared__ __align__(16) char lds[32768];   // [2] x (A 8KB + B 8KB)
    int t = threadIdx.x;
    int l = t & 63, w = t >> 6;
    int lr = l & 15, g = l >> 4;

    int f = blockIdx.x;                 // 512 blocks
    int xcd = f & 7, s = f >> 3;
    int combo = xcd * 2 + (s >> 5);     // 0..15
    int ib = s & 31;
    int b = combo & 3, h = combo >> 2;
    int i_base = ib * 64;
    int hc = h * 64;

    const ushort* Eb = E + (size_t)(h * 4 + b) * 2048 * 2048;
    int slot = t & 7, trow = t >> 3;

    const ushort* srcA[2];
    const ushort* srcB[2];
#pragma unroll
    for (int q = 0; q < 2; ++q) {
        int arow = q * 32 + trow;
        srcA[q] = Eb + (size_t)(i_base + arow) * 2048 + ((slot ^ (arow & 7)) << 3);
        int cl = q * 32 + trow;
        srcB[q] = Vt + (size_t)(b * 256 + hc + cl) * 2048 + ((slot ^ (cl & 7)) << 3);
    }
    auto STAGE = [&](int buf) {
#pragma unroll
        for (int q = 0; q < 2; ++q)
            GLOAD_LDS16(srcA[q], lds + buf * 16384 + q * 4096 + t * 16);
#pragma unroll
        for (int q = 0; q < 2; ++q)
            GLOAD_LDS16(srcB[q], lds + buf * 16384 + 8192 + q * 4096 + t * 16);
#pragma unroll
        for (int q = 0; q < 2; ++q) { srcA[q] += 64; srcB[q] += 64; }
    };

    f32x4 acc[4] = {};
    f32x4 accd = {};
    short8 ones = {0x3F80, 0x3F80, 0x3F80, 0x3F80, 0x3F80, 0x3F80, 0x3F80, 0x3F80};

    int arow = w * 16 + lr;
    int aoff = arow * 128;
    int sw_a = (arow & 7) << 4;

    STAGE(0);
    for (int c = 0; c < 32; ++c) {
        __syncthreads();
        if (c + 1 < 32) STAGE((c + 1) & 1);
        const char* As = lds + (c & 1) * 16384;
        const char* Bs = As + 8192;

        short8 a0 = *(const short8*)(As + aoff + ((g * 16) ^ sw_a));
        short8 a1 = *(const short8*)(As + aoff + ((64 + g * 16) ^ sw_a));
        accd = __builtin_amdgcn_mfma_f32_16x16x32_bf16(a0, ones, accd, 0, 0, 0);
        accd = __builtin_amdgcn_mfma_f32_16x16x32_bf16(a1, ones, accd, 0, 0, 0);
#pragma unroll
        for (int n = 0; n < 4; ++n) {
            int cc = n * 16 + lr;
            const char* cb = Bs + cc * 128;
            int sw = (cc & 7) << 4;
            short8 b0 = *(const short8*)(cb + ((g * 16) ^ sw));
            short8 b1 = *(const short8*)(cb + ((64 + g * 16) ^ sw));
            acc[n] = __builtin_amdgcn_mfma_f32_16x16x32_bf16(a0, b0, acc[n], 0, 0, 0);
            acc[n] = __builtin_amdgcn_mfma_f32_16x16x32_bf16(a1, b1, acc[n], 0, 0, 0);
        }
    }

#pragma unroll
    for (int r = 0; r < 4; ++r) {
        float invd = 1.f / (accd[r] + 1e-8f);
        int row = i_base + w * 16 + g * 4 + r;
        size_t rb = ((size_t)b * N_ + row) * 256 + hc + lr;
#pragma unroll
        for (int n = 0; n < 4; ++n)
            attb[rb + n * 16] = f2bf(acc[n][r] * invd);
    }
}

// ---------------------------------------------------------------------------
// gemmM: MODE 3 (V-proj for layer 0, transposed bf16 out); MODE 4 (final
// out-MLP fused with out_W2 projection).
// ---------------------------------------------------------------------------
template <int KD, int COLS, int MODE>
__global__ __launch_bounds__(256) void gemmM(const ushort* __restrict__ A,
                                             const ushort* __restrict__ Bt,
                                             const float* __restrict__ bias,
                                             const float* __restrict__ resid,
                                             const float* __restrict__ lng,
                                             const float* __restrict__ lnb,
                                             ushort* __restrict__ outb,
                                             float* __restrict__ outf) {
    __shared__ __align__(16) char lds[69632];
    int t = threadIdx.x;
    int l = t & 63, w = t >> 6;
    int lr = l & 15, g = l >> 4;
    int row0 = blockIdx.x * 16;
    f32x4 acc[4] = {};

    const ushort* srcA = A + (size_t)(row0 + (t >> 3)) * KD + (((t & 7) ^ ((t >> 3) & 7)) << 3);
    const ushort* srcB[8];
#pragma unroll
    for (int q = 0; q < 8; ++q) {
        int cl = q * 32 + (t >> 3);
        srcB[q] = Bt + (size_t)cl * KD + (((t & 7) ^ (cl & 7)) << 3);
    }

    auto STAGE = [&](int buf) {
        if (t < 128) GLOAD_LDS16(srcA, lds + buf * 2048 + t * 16);
#pragma unroll
        for (int q = 0; q < 8; ++q)
            GLOAD_LDS16(srcB[q], lds + 4096 + buf * 32768 + q * 4096 + t * 16);
        srcA += 64;
#pragma unroll
        for (int q = 0; q < 8; ++q) srcB[q] += 64;
    };

    int sw_a = (lr & 7) << 4;
    int aoff = lr * 128;
    constexpr int CH = KD / 64;

    STAGE(0);
#pragma unroll
    for (int c = 0; c < CH; ++c) {
        __syncthreads();
        if (c + 1 < CH) STAGE((c + 1) & 1);
        const char* As = lds + (c & 1) * 2048;
        const char* Ws = lds + 4096 + (c & 1) * 32768;

        short8 a0 = *(const short8*)(As + aoff + ((g * 16) ^ sw_a));
        short8 a1 = *(const short8*)(As + aoff + ((64 + g * 16) ^ sw_a));
#pragma unroll
        for (int n = 0; n < 4; ++n) {
            int cc = w * 64 + n * 16 + lr;
            const char* cb = Ws + cc * 128;
            int sw = (cc & 7) << 4;
            short8 b0 = *(const short8*)(cb + ((g * 16) ^ sw));
            short8 b1 = *(const short8*)(cb + ((64 + g * 16) ^ sw));
            acc[n] = __builtin_amdgcn_mfma_f32_16x16x32_bf16(a0, b0, acc[n], 0, 0, 0);
            acc[n] = __builtin_amdgcn_mfma_f32_16x16x32_bf16(a1, b1, acc[n], 0, 0, 0);
        }
    }
    __syncthreads();

    if constexpr (MODE == 3) {
        ushort(*Ts)[24] = (ushort(*)[24])lds;
#pragma unroll
        for (int n = 0; n < 4; ++n) {
            int c = w * 64 + n * 16 + lr;
            float bi = bias[c];
#pragma unroll
            for (int r = 0; r < 4; ++r)
                Ts[c][g * 4 + r] = f2bf(acc[n][r] + bi);
        }
        __syncthreads();
        {
            int c = t;
            int b = row0 >> 11;
            int n0 = row0 & 2047;
            ushort* dst = outb + ((size_t)(b * 256 + c)) * 2048 + n0;
            *(uint4*)dst = *(uint4*)&Ts[c][0];
            *(uint4*)(dst + 8) = *(uint4*)&Ts[c][8];
        }
    } else {  // MODE 4
        const float* W2 = resid;    // [256][3]
        const float* b2 = lng;      // [3]
        ushort(*Ts)[264] = (ushort(*)[264])lds;
#pragma unroll
        for (int n = 0; n < 4; ++n) {
            int c = w * 64 + n * 16 + lr;
            float bi = bias[c];
#pragma unroll
            for (int r = 0; r < 4; ++r)
                Ts[g * 4 + r][c] = f2bf(fmaxf(acc[n][r] + bi, 0.f));
        }
        __syncthreads();
        int row = t >> 4, s = t & 15;
        float p0 = 0.f, p1 = 0.f, p2 = 0.f;
#pragma unroll
        for (int e = 0; e < 16; ++e) {
            float x = bf2f(Ts[row][s * 16 + e]);
            const float* wr = &W2[(s * 16 + e) * 3];
            p0 += x * wr[0];
            p1 += x * wr[1];
            p2 += x * wr[2];
        }
#pragma unroll
        for (int off = 1; off < 16; off <<= 1) {
            p0 += __shfl_xor(p0, off, 64);
            p1 += __shfl_xor(p1, off, 64);
            p2 += __shfl_xor(p2, off, 64);
        }
        if (s == 0) {
            int gr = row0 + row;
            outf[gr * 3 + 0] = p0 + b2[0];
            outf[gr * 3 + 1] = p1 + b2[1];
            outf[gr * 3 + 2] = p2 + b2[2];
        }
    }
}

// ---------------------------------------------------------------------------
// gemm_layer: attn-proj -> LN1 -> FFN1 -> ReLU -> FFN2 -> LN2 -> V(l+1).
// Per 16-row block; x1 stays in regs+LDS (no global round-trip); weights
// stream via reg-dbuf prefetched across phase boundaries.
// LDS: Aa[2x2K] | Asp 8K | Wsp 32K | hid/Ts 16K = 60KB.
// ---------------------------------------------------------------------------
__global__ __launch_bounds__(256) void gemm_layer(
        const ushort* __restrict__ attb,
        const ushort* __restrict__ Wat, const float* __restrict__ pb,
        float* __restrict__ feats,
        const float* __restrict__ ln1g, const float* __restrict__ ln1b,
        const ushort* __restrict__ W1t, const float* __restrict__ b1,
        const ushort* __restrict__ W2t, const float* __restrict__ b2,
        const float* __restrict__ ln2g, const float* __restrict__ ln2b,
        ushort* __restrict__ featsb,
        const ushort* __restrict__ WvN, const float* __restrict__ vbN,
        ushort* __restrict__ Vt) {
    __shared__ __align__(16) char lds[61440];
    char* Aa = lds;             // 4KB (2 bufs); red1/red2 overlay after P0
    char* Asp = lds + 4096;     // 8KB: x1 bf16, later x2 bf16
    char* Wsp = lds + 12288;    // 32KB
    char* hidp = lds + 45056;   // 16KB; Ts overlays in P3

    int t = threadIdx.x;
    int l = t & 63, w = t >> 6;
    int lr = l & 15, g = l >> 4;
    int row0 = blockIdx.x * 16;
    int sw_a = (lr & 7) << 4;
    int trow = t >> 3, slot = t & 7;

    uint4 wr0, wr1, wr2, wr3, wr4, wr5, wr6, wr7;
    auto WLOADG = [&](const ushort* Wb, int stride, int colbase, int c) {
        const ushort* base = Wb + c * 64;
#pragma unroll
        for (int q = 0; q < 8; ++q) {
            int cl = colbase + q * 32 + trow;
            uint4 v = *(const uint4*)(base + (size_t)cl * stride + ((slot ^ (cl & 7)) << 3));
            if (q == 0) wr0 = v; else if (q == 1) wr1 = v; else if (q == 2) wr2 = v;
            else if (q == 3) wr3 = v; else if (q == 4) wr4 = v; else if (q == 5) wr5 = v;
            else if (q == 6) wr6 = v; else wr7 = v;
        }
    };
    auto WSTORE = [&]() {
        *(uint4*)(Wsp + 0 * 4096 + t * 16) = wr0;
        *(uint4*)(Wsp + 1 * 4096 + t * 16) = wr1;
        *(uint4*)(Wsp + 2 * 4096 + t * 16) = wr2;
        *(uint4*)(Wsp + 3 * 4096 + t * 16) = wr3;
        *(uint4*)(Wsp + 4 * 4096 + t * 16) = wr4;
        *(uint4*)(Wsp + 5 * 4096 + t * 16) = wr5;
        *(uint4*)(Wsp + 6 * 4096 + t * 16) = wr6;
        *(uint4*)(Wsp + 7 * 4096 + t * 16) = wr7;
    };

    // ---- P0: attn-proj (KD=256), A = attb staged, W = Wat reg-dbuf ----
    const ushort* srcA = attb + (size_t)(row0 + trow) * 256 + ((slot ^ (trow & 7)) << 3);
    auto STAGEA = [&](int buf, int c) {
        if (t < 128) GLOAD_LDS16(srcA + c * 64, Aa + buf * 2048 + t * 16);
    };

    f32x4 acc[4] = {};
    STAGEA(0, 0);
    WLOADG(Wat, 256, 0, 0);
#pragma unroll
    for (int c = 0; c < 4; ++c) {
        __syncthreads();            // Aa[c&1] drained; Wsp free
        WSTORE();
        __syncthreads();            // Wsp visible
        if (c < 3) { WLOADG(Wat, 256, 0, c + 1); STAGEA((c + 1) & 1, c + 1); }
        else WLOADG(W1t, 256, 0, 0);    // prefetch P1 first chunk

        const char* As = Aa + (c & 1) * 2048;
        short8 a0 = *(const short8*)(As + lr * 128 + ((g * 16) ^ sw_a));
        short8 a1 = *(const short8*)(As + lr * 128 + ((64 + g * 16) ^ sw_a));
#pragma unroll
        for (int n = 0; n < 4; ++n) {
            int cc = w * 64 + n * 16 + lr;
            const char* cb = Wsp + cc * 128;
            int sw = (cc & 7) << 4;
            short8 b0 = *(const short8*)(cb + ((g * 16) ^ sw));
            short8 b1 = *(const short8*)(cb + ((64 + g * 16) ^ sw));
            acc[n] = __builtin_amdgcn_mfma_f32_16x16x32_bf16(a0, b0, acc[n], 0, 0, 0);
            acc[n] = __builtin_amdgcn_mfma_f32_16x16x32_bf16(a1, b1, acc[n], 0, 0, 0);
        }
    }
    __syncthreads();

    // ---- LN1 (x1 kept in regs; bf16 to Asp) ----
    float* red1 = (float*)lds;
    float* red2 = (float*)(lds + 512);
    float x1v[4][4];
    {
        float s1[4] = {0.f, 0.f, 0.f, 0.f}, s2[4] = {0.f, 0.f, 0.f, 0.f};
#pragma unroll
        for (int n = 0; n < 4; ++n) {
            int c = w * 64 + n * 16 + lr;
            float bi = pb[c];
#pragma unroll
            for (int r = 0; r < 4; ++r) {
                int row = row0 + g * 4 + r;
                float v = acc[n][r] + bi + feats[(size_t)row * 256 + c];
                x1v[n][r] = v;
                s1[r] += v;
                s2[r] += v * v;
            }
        }
#pragma unroll
        for (int off = 1; off < 16; off <<= 1) {
#pragma unroll
            for (int r = 0; r < 4; ++r) {
                s1[r] += __shfl_xor(s1[r], off, 64);
                s2[r] += __shfl_xor(s2[r], off, 64);
            }
        }
        if (lr == 0) {
#pragma unroll
            for (int r = 0; r < 4; ++r) {
                red1[(g * 4 + r) * 4 + w] = s1[r];
                red2[(g * 4 + r) * 4 + w] = s2[r];
            }
        }
        __syncthreads();
#pragma unroll
        for (int n = 0; n < 4; ++n) {
            int c = w * 64 + n * 16 + lr;
            float gg = ln1g[c], bb = ln1b[c];
#pragma unroll
            for (int r = 0; r < 4; ++r) {
                int rr = g * 4 + r;
                float m1 = red1[rr * 4] + red1[rr * 4 + 1] + red1[rr * 4 + 2] + red1[rr * 4 + 3];
                float m2 = red2[rr * 4] + red2[rr * 4 + 1] + red2[rr * 4 + 2] + red2[rr * 4 + 3];
                float mu = m1 * (1.f / 256.f);
                float var = m2 * (1.f / 256.f) - mu * mu;
                float rstd = rsqrtf(var + 1e-5f);
                float o = (x1v[n][r] - mu) * rstd * gg + bb;
                x1v[n][r] = o;                       // x1 (resid for LN2)
                *(ushort*)(Asp + rr * 512 + ((2 * c) ^ ((rr & 7) << 4))) = f2bf(o);
            }
        }
    }

    // ---- P1: FFN1 (KD=256, COLS=512), A = Asp, relu -> hid LDS ----
#pragma unroll
    for (int ch = 0; ch < 2; ++ch) {
        f32x4 acc1[4] = {};
#pragma unroll
        for (int c = 0; c < 4; ++c) {
            __syncthreads();
            WSTORE();
            __syncthreads();
            if (c < 3) WLOADG(W1t, 256, ch * 256, c + 1);
            else if (ch == 0) WLOADG(W1t, 256, 256, 0);
            else WLOADG(W2t, 512, 0, 0);

            short8 a0 = *(const short8*)(Asp + lr * 512 + ((c * 128 + g * 16) ^ sw_a));
            short8 a1 = *(const short8*)(Asp + lr * 512 + ((c * 128 + 64 + g * 16) ^ sw_a));
#pragma unroll
            for (int n = 0; n < 4; ++n) {
                int cc = w * 64 + n * 16 + lr;
                const char* cb = Wsp + cc * 128;
                int sw = (cc & 7) << 4;
                short8 b0 = *(const short8*)(cb + ((g * 16) ^ sw));
                short8 b1 = *(const short8*)(cb + ((64 + g * 16) ^ sw));
                acc1[n] = __builtin_amdgcn_mfma_f32_16x16x32_bf16(a0, b0, acc1[n], 0, 0, 0);
                acc1[n] = __builtin_amdgcn_mfma_f32_16x16x32_bf16(a1, b1, acc1[n], 0, 0, 0);
            }
        }
#pragma unroll
        for (int n = 0; n < 4; ++n) {
            int c = w * 64 + n * 16 + lr;
            float bi = b1[ch * 256 + c];
#pragma unroll
            for (int r = 0; r < 4; ++r) {
                int rw = g * 4 + r;
                float v = fmaxf(acc1[n][r] + bi, 0.f);
                int byte = rw * 1024 + (((ch * 256 + c) * 2) ^ ((rw & 7) << 4));
                *(ushort*)(hidp + byte) = f2bf(v);
            }
        }
    }

    // ---- P2: FFN2 (KD=512), A = hid LDS ----
    f32x4 acc2[4] = {};
#pragma unroll
    for (int c = 0; c < 8; ++c) {
        __syncthreads();
        WSTORE();
        __syncthreads();
        if (c < 7) WLOADG(W2t, 512, 0, c + 1);
        else if (WvN) WLOADG(WvN, 256, 0, 0);

        short8 a0 = *(const short8*)(hidp + lr * 1024 + ((c * 128 + g * 16) ^ sw_a));
        short8 a1 = *(const short8*)(hidp + lr * 1024 + ((c * 128 + 64 + g * 16) ^ sw_a));
#pragma unroll
        for (int n = 0; n < 4; ++n) {
            int cc = w * 64 + n * 16 + lr;
            const char* cb = Wsp + cc * 128;
            int sw = (cc & 7) << 4;
            short8 b0 = *(const short8*)(cb + ((g * 16) ^ sw));
            short8 b1 = *(const short8*)(cb + ((64 + g * 16) ^ sw));
            acc2[n] = __builtin_amdgcn_mfma_f32_16x16x32_bf16(a0, b0, acc2[n], 0, 0, 0);
            acc2[n] = __builtin_amdgcn_mfma_f32_16x16x32_bf16(a1, b1, acc2[n], 0, 0, 0);
        }
    }
    __syncthreads();

    // ---- LN2 (resid = x1 regs) -> feats fp32+bf16 global; x2 bf16 -> Asp ----
#pragma unroll
    for (int n = 0; n < 4; ++n) {
        int c = w * 64 + n * 16 + lr;
        float bi = b2[c];
#pragma unroll
        for (int r = 0; r < 4; ++r) {
            float v = acc2[n][r] + bi + x1v[n][r];
            acc2[n][r] = v;
        }
    }
    {
        float s1[4] = {0.f, 0.f, 0.f, 0.f}, s2[4] = {0.f, 0.f, 0.f, 0.f};
#pragma unroll
        for (int n = 0; n < 4; ++n)
#pragma unroll
            for (int r = 0; r < 4; ++r) {
                s1[r] += acc2[n][r];
                s2[r] += acc2[n][r] * acc2[n][r];
            }
#pragma unroll
        for (int off = 1; off < 16; off <<= 1) {
#pragma unroll
            for (int r = 0; r < 4; ++r) {
                s1[r] += __shfl_xor(s1[r], off, 64);
                s2[r] += __shfl_xor(s2[r], off, 64);
            }
        }
        if (lr == 0) {
#pragma unroll
            for (int r = 0; r < 4; ++r) {
                red1[(g * 4 + r) * 4 + w] = s1[r];
                red2[(g * 4 + r) * 4 + w] = s2[r];
            }
        }
        __syncthreads();
#pragma unroll
        for (int n = 0; n < 4; ++n) {
            int c = w * 64 + n * 16 + lr;
            float gg = ln2g[c], bb = ln2b[c];
#pragma unroll
            for (int r = 0; r < 4; ++r) {
                int rr = g * 4 + r;
                float m1 = red1[rr * 4] + red1[rr * 4 + 1] + red1[rr * 4 + 2] + red1[rr * 4 + 3];
                float m2 = red2[rr * 4] + red2[rr * 4 + 1] + red2[rr * 4 + 2] + red2[rr * 4 + 3];
                float mu = m1 * (1.f / 256.f);
                float var = m2 * (1.f / 256.f) - mu * mu;
                float rstd = rsqrtf(var + 1e-5f);
                int row = row0 + rr;
                float o = (acc2[n][r] - mu) * rstd * gg + bb;
                feats[(size_t)row * 256 + c] = o;
                ushort ob = f2bf(o);
                featsb[(size_t)row * 256 + c] = ob;
                *(ushort*)(Asp + rr * 512 + ((2 * c) ^ ((rr & 7) << 4))) = ob;
            }
        }
    }

    // ---- P3: V(l+1) = x2 @ WvN (KD=256), transposed bf16 -> Vt ----
    if (WvN) {
        f32x4 acc3[4] = {};
#pragma unroll
        for (int c = 0; c < 4; ++c) {
            __syncthreads();
            WSTORE();
            __syncthreads();
            if (c < 3) WLOADG(WvN, 256, 0, c + 1);

            short8 a0 = *(const short8*)(Asp + lr * 512 + ((c * 128 + g * 16) ^ sw_a));
            short8 a1 = *(const short8*)(Asp + lr * 512 + ((c * 128 + 64 + g * 16) ^ sw_a));
#pragma unroll
            for (int n = 0; n < 4; ++n) {
                int cc = w * 64 + n * 16 + lr;
                const char* cb = Wsp + cc * 128;
                int sw = (cc & 7) << 4;
                short8 b0 = *(const short8*)(cb + ((g * 16) ^ sw));
                short8 b1 = *(const short8*)(cb + ((64 + g * 16) ^ sw));
                acc3[n] = __builtin_amdgcn_mfma_f32_16x16x32_bf16(a0, b0, acc3[n], 0, 0, 0);
                acc3[n] = __builtin_amdgcn_mfma_f32_16x16x32_bf16(a1, b1, acc3[n], 0, 0, 0);
            }
        }
        __syncthreads();
        ushort(*Ts)[24] = (ushort(*)[24])hidp;   // 12KB <= 16KB
#pragma unroll
        for (int n = 0; n < 4; ++n) {
            int c = w * 64 + n * 16 + lr;
            float bi = vbN[c];
#pragma unroll
            for (int r = 0; r < 4; ++r)
                Ts[c][g * 4 + r] = f2bf(acc3[n][r] + bi);
        }
        __syncthreads();
        {
            int c = t;
            int b = row0 >> 11;
            int n0 = row0 & 2047;
            ushort* dst = Vt + ((size_t)(b * 256 + c)) * 2048 + n0;
            *(uint4*)dst = *(uint4*)&Ts[c][0];
            *(uint4*)(dst + 8) = *(uint4*)&Ts[c][8];
        }
    }
}

// ---------------------------------------------------------------------------
extern "C" void kernel_launch(void* const* d_in, const int* in_sizes, int n_in,
                              void* d_out, int out_size, void* d_ws, size_t ws_size,
                              hipStream_t stream) {
    const float* lat    = (const float*)d_in[0];
    const float* xc     = (const float*)d_in[1];
    const float* emb    = (const float*)d_in[2];
    const float* in_W   = (const float*)d_in[3];
    const float* in_b   = (const float*)d_in[4];
    const float* val_W  = (const float*)d_in[5];
    const float* val_b  = (const float*)d_in[6];
    const float* attn_W = (const float*)d_in[7];
    const float* attn_b = (const float*)d_in[8];
    const float* ln1_g  = (const float*)d_in[9];
    const float* ln1_b  = (const float*)d_in[10];
    const float* ln2_g  = (const float*)d_in[11];
    const float* ln2_b  = (const float*)d_in[12];
    const float* ffn_W1 = (const float*)d_in[13];
    const float* ffn_b1 = (const float*)d_in[14];
    const float* ffn_W2 = (const float*)d_in[15];
    const float* ffn_b2 = (const float*)d_in[16];
    const float* out_W1 = (const float*)d_in[17];
    const float* out_b1 = (const float*)d_in[18];
    const float* out_W2 = (const float*)d_in[19];
    const float* out_b2 = (const float*)d_in[20];

    char* W = (char*)d_ws;
    float*  feats  = (float*)W;                                // 8 MB
    ushort* featsb = (ushort*)(W + (8u << 20));                // 4 MB
    ushort* attb   = (ushort*)(W + (12u << 20));               // 4 MB
    ushort* Vt     = (ushort*)(W + (16u << 20));               // 4 MB
    ushort* wp     = (ushort*)(W + (20u << 20));               // 3.2 MB
    ushort* E      = (ushort*)(W + (24u << 20));               // 128 MiB
    ushort* Wvt  = wp;
    ushort* Wat  = wp + 262144;
    ushort* W1t  = wp + 524288;
    ushort* W2t  = wp + 1048576;
    ushort* Wo1t = wp + 1572864;

    pack_weights<<<6400, 256, 0, stream>>>(val_W, attn_W, ffn_W1, ffn_W2, out_W1, wp);
    input_mlp<<<R_ / 8, 256, 0, stream>>>(xc, emb, lat, in_W, in_b, feats, featsb);
    ebuild<<<dim3(4, 32, B_), 256, 0, stream>>>(xc, E);

    gemmM<256, 256, 3><<<dim3(R_ / 16, 1), 256, 0, stream>>>(
        featsb, Wvt, val_b, nullptr, nullptr, nullptr, Vt, nullptr);

    for (int l = 0; l < LAYERS_; ++l) {
        pv_gemm<<<512, 256, 0, stream>>>(E, Vt, attb);
        const ushort* WvN = (l + 1 < LAYERS_) ? (Wvt + (l + 1) * 65536) : nullptr;
        const float* vbN = val_b + ((l + 1 < LAYERS_) ? (l + 1) * 256 : 0);
        gemm_layer<<<R_ / 16, 256, 0, stream>>>(
            attb, Wat + l * 65536, attn_b + l * 256,
            feats, ln1_g + l * 256, ln1_b + l * 256,
            W1t + l * 131072, ffn_b1 + l * 512,
            W2t + l * 131072, ffn_b2 + l * 256,
            ln2_g + l * 256, ln2_b + l * 256,
            featsb, WvN, vbN, Vt);
    }

    gemmM<256, 256, 4><<<dim3(R_ / 16, 1), 256, 0, stream>>>(
        featsb, Wo1t, out_b1, out_W2, out_b2, nullptr, nullptr, (float*)d_out);
}